// Round 12
// baseline (280.658 us; speedup 1.0000x reference)
//
#include <hip/hip_runtime.h>
#include <hip/hip_bf16.h>

#define B_ 8
#define T_ 1024
#define D_ 256
#define H_ 8
#define KD_ 256
#define HK_ 2048
#define FF_ 1024
#define WIN_ 64
#define BT_ 8192
#define SX_ 10240   // merged projection row: [lQ|lK|lV|gK|gV]

using bf16 = __hip_bfloat16;
typedef float f32x4 __attribute__((ext_vector_type(4)));
typedef short s16x8 __attribute__((ext_vector_type(8)));

__device__ inline float b2f(bf16 h) { return __bfloat162float(h); }
__device__ inline float bs2f(short s) {
    unsigned int u = ((unsigned int)(unsigned short)s) << 16;
    return __builtin_bit_cast(float, u);
}
__device__ inline float us2f(unsigned short s) {
    unsigned int u = ((unsigned int)s) << 16;
    return __builtin_bit_cast(float, u);
}
__device__ inline unsigned short fbits(float x) { bf16 h = __float2bfloat16(x); return __builtin_bit_cast(unsigned short, h); }

// async global->LDS, 16B per lane; lds base wave-uniform, lane l lands at base + l*16
__device__ __forceinline__ void stage16(const void* g, void* l) {
    __builtin_amdgcn_global_load_lds((const __attribute__((address_space(1))) void*)g,
                                     (__attribute__((address_space(3))) void*)l, 16, 0, 0);
}

// ---------------- elementwise f32 -> bf16 ----------------
__global__ __launch_bounds__(256) void f32_to_bf16_vec(const float* __restrict__ in, bf16* __restrict__ out, int n) {
    int i = (blockIdx.x * 256 + threadIdx.x) * 4;
    if (i + 3 < n) {
        float4 v = *(const float4*)(in + i);
        ushort4 o;
        o.x = fbits(v.x); o.y = fbits(v.y); o.z = fbits(v.z); o.w = fbits(v.w);
        *(ushort4*)(out + i) = o;
    }
}

// ---------------- fused weight transposes: in f32[R][C] -> out bf16[C][R], row stride os ----------------
struct TJob { const float* in; bf16* out; int R; int C; int os; int tile_start; };
struct TJobs { TJob j[10]; int total; };

__global__ void transpose_all(TJobs js) {
    __shared__ float tile[32][33];
    int bid = blockIdx.x;
    int ji = 0;
    while (ji < 9 && bid >= js.j[ji + 1].tile_start) ji++;
    TJob jb = js.j[ji];
    int t = bid - jb.tile_start;
    int tiles_x = jb.C / 32;
    int cb = (t % tiles_x) * 32, rb = (t / tiles_x) * 32;
    for (int k = 0; k < 4; k++) {
        int r = threadIdx.y + k * 8;
        tile[r][threadIdx.x] = jb.in[(size_t)(rb + r) * jb.C + cb + threadIdx.x];
    }
    __syncthreads();
    for (int k = 0; k < 4; k++) {
        int r = threadIdx.y + k * 8;
        jb.out[(size_t)(cb + r) * jb.os + rb + threadIdx.x] = __float2bfloat16(tile[threadIdx.x][r]);
    }
}

// bias concat: bcat10[10240] = [lbq | lbk | lbv | gbk | gbv]
__global__ __launch_bounds__(256) void concat_bias10(const float* a0, const float* a1, const float* a2,
                                                     const float* a3, const float* a4, float* out) {
    int i = blockIdx.x * 256 + threadIdx.x;
    int seg = i >> 11, off = i & 2047;
    const float* p = seg == 0 ? a0 : seg == 1 ? a1 : seg == 2 ? a2 : seg == 3 ? a3 : a4;
    out[i] = p[off];
}

// ---------------- dbuf 2-phase GEMM with T2 LDS swizzle (proven round-9/11) ----------------
// C[M][N] = A[M][K] * Bt[N][K]^T + bias. 128xBN tile, BK=64, 4 waves. bf16 out.
// MODE 1: plain; MODE 2: relu.
template <int MODE, int BN>
__global__ __launch_bounds__(256) void gemm128(const bf16* __restrict__ A, const bf16* __restrict__ Bt,
                                               const float* __restrict__ bias, bf16* __restrict__ C,
                                               int M, int N, int K) {
    constexpr int NF = BN / 32;
    constexpr int ABUF = 128 * 64;
    constexpr int BBUF = BN * 64;
    constexpr int BUFE = ABUF + BBUF;
    constexpr int EC = BN + 8;
    constexpr int ARENA_E = (2 * BUFE > 128 * EC) ? 2 * BUFE : 128 * EC;
    __shared__ __align__(16) bf16 arena[ARENA_E];
    const int tid = threadIdx.x;
    const int w = tid >> 6, l = tid & 63;
    const int m0 = blockIdx.y * 128, n0 = blockIdx.x * BN;
    const int wm = (w >> 1) * 64, wn = (w & 1) * (BN / 2);
    const int srow = w * 8 + (l >> 3);
    const int scol = ((l & 7) ^ (l >> 3)) * 8;   // T2: pre-swizzled source column
    const int ldsOff = w * 512;
    const int nt = K / 64;

    auto stageT = [&](int buf, int k0) {
        bf16* Ad = arena + buf * BUFE;
        bf16* Bd = Ad + ABUF;
#pragma unroll
        for (int j = 0; j < 4; j++)
            stage16(A + (size_t)(m0 + j * 32 + srow) * K + k0 + scol, &Ad[ldsOff + j * 2048]);
#pragma unroll
        for (int j = 0; j < NF; j++)
            stage16(Bt + (size_t)(n0 + j * 32 + srow) * K + k0 + scol, &Bd[ldsOff + j * 2048]);
    };

    f32x4 acc[4][NF] = {};
    stageT(0, 0);
    __syncthreads();
    int cur = 0;
    for (int t = 0; t < nt; t++) {
        if (t + 1 < nt) stageT(cur ^ 1, (t + 1) * 64);
        const bf16* As = arena + cur * BUFE;
        const bf16* Bs = As + ABUF;
#pragma unroll
        for (int ks = 0; ks < 2; ks++) {
            s16x8 a[4], b[NF];
#pragma unroll
            for (int mf = 0; mf < 4; mf++) {
                int ar = wm + mf * 16 + (l & 15);
                int ch = (ks * 4 + (l >> 4)) ^ (ar & 7);
                a[mf] = *(const s16x8*)&As[ar * 64 + ch * 8];
            }
#pragma unroll
            for (int nf = 0; nf < NF; nf++) {
                int br = wn + nf * 16 + (l & 15);
                int ch = (ks * 4 + (l >> 4)) ^ (br & 7);
                b[nf] = *(const s16x8*)&Bs[br * 64 + ch * 8];
            }
            __builtin_amdgcn_s_setprio(1);
#pragma unroll
            for (int mf = 0; mf < 4; mf++)
#pragma unroll
                for (int nf = 0; nf < NF; nf++)
                    acc[mf][nf] = __builtin_amdgcn_mfma_f32_16x16x32_bf16(a[mf], b[nf], acc[mf][nf], 0, 0, 0);
            __builtin_amdgcn_s_setprio(0);
        }
        __syncthreads();
        cur ^= 1;
    }
    bf16* Es = arena;
#pragma unroll
    for (int mf = 0; mf < 4; mf++)
#pragma unroll
        for (int nf = 0; nf < NF; nf++)
#pragma unroll
            for (int r = 0; r < 4; r++) {
                int row = wm + mf * 16 + (l >> 4) * 4 + r;
                int col = wn + nf * 16 + (l & 15);
                float v = acc[mf][nf][r] + bias[n0 + col];
                if (MODE == 2) v = fmaxf(v, 0.f);
                Es[row * EC + col] = __float2bfloat16(v);
            }
    __syncthreads();
    constexpr int RPC = BN / 8;
    constexpr int CPT = (128 * BN) / (256 * 8);
#pragma unroll
    for (int c = 0; c < CPT; c++) {
        int lin = c * 256 + tid;
        int row = lin / RPC, cc = lin - row * RPC;
        s16x8 v = *(const s16x8*)&Es[row * EC + cc * 8];
        *(s16x8*)(C + (size_t)(m0 + row) * N + n0 + cc * 8) = v;
    }
}

// ---------------- local windowed attention (proven; XW stride) ----------------
__global__ __launch_bounds__(256) void local_attn(const bf16* __restrict__ XW, bf16* __restrict__ O) {
    __shared__ bf16 U[256 * 72];
    __shared__ bf16 Ps[64][136];
    const int tid = threadIdx.x, l = tid & 63, w = tid >> 6;
    const int qt = blockIdx.x, bh = blockIdx.y;
    const int b = bh >> 3, h = bh & 7;
    const int qs = qt * 64;
    const int r0 = w * 16;
    const int lrow = tid >> 2, lc4 = (tid & 3) * 8;
    const size_t obase = (size_t)b * T_ * HK_ + h * KD_;

    s16x8 qa[8];
    {
        const bf16* qbase = XW + (size_t)(b * T_ + qs + r0 + (l & 15)) * SX_ + h * KD_ + (l >> 4) * 8;
#pragma unroll
        for (int ks = 0; ks < 8; ks++) qa[ks] = *(const s16x8*)(qbase + ks * 32);
    }

    bf16(*Ks)[264] = (bf16(*)[264])U;
    {
        int tk = qs - 64 + lrow;
        const bf16* krow = XW + (size_t)(b * T_ + tk) * SX_ + 2048 + h * KD_;
#pragma unroll
        for (int c = 0; c < 8; c++) {
            int col = lc4 + c * 32;
            uint4 val = {0, 0, 0, 0};
            if (tk >= 0) val = *(const uint4*)(krow + col);
            *(uint4*)&Ks[lrow][col] = val;
        }
    }
    __syncthreads();
    f32x4 sacc[8];
#pragma unroll
    for (int f = 0; f < 8; f++) sacc[f] = (f32x4){0.f, 0.f, 0.f, 0.f};
    __builtin_amdgcn_s_setprio(1);
#pragma unroll
    for (int nf = 0; nf < 4; nf++)
#pragma unroll
        for (int ks = 0; ks < 8; ks++) {
            s16x8 bb = *(const s16x8*)&Ks[nf * 16 + (l & 15)][ks * 32 + (l >> 4) * 8];
            sacc[nf] = __builtin_amdgcn_mfma_f32_16x16x32_bf16(qa[ks], bb, sacc[nf], 0, 0, 0);
        }
    __builtin_amdgcn_s_setprio(0);
    __syncthreads();
    {
        const bf16* krow = XW + (size_t)(b * T_ + qs + lrow) * SX_ + 2048 + h * KD_;
#pragma unroll
        for (int c = 0; c < 8; c++) {
            int col = lc4 + c * 32;
            *(uint4*)&Ks[lrow][col] = *(const uint4*)(krow + col);
        }
    }
    __syncthreads();
    __builtin_amdgcn_s_setprio(1);
#pragma unroll
    for (int nf = 0; nf < 4; nf++)
#pragma unroll
        for (int ks = 0; ks < 8; ks++) {
            s16x8 bb = *(const s16x8*)&Ks[nf * 16 + (l & 15)][ks * 32 + (l >> 4) * 8];
            sacc[4 + nf] = __builtin_amdgcn_mfma_f32_16x16x32_bf16(qa[ks], bb, sacc[4 + nf], 0, 0, 0);
        }
    __builtin_amdgcn_s_setprio(0);

    uint4 vreg[8];
    {
        int tk = qs - 64 + lrow;
        const bf16* vrow = XW + (size_t)(b * T_ + tk) * SX_ + 4096 + h * KD_;
#pragma unroll
        for (int c = 0; c < 8; c++) {
            uint4 v = {0, 0, 0, 0};
            if (tk >= 0) v = *(const uint4*)(vrow + lc4 + c * 32);
            vreg[c] = v;
        }
    }

#pragma unroll
    for (int r = 0; r < 4; r++) {
        int i = qs + r0 + (l >> 4) * 4 + r;
#pragma unroll
        for (int f = 0; f < 8; f++) {
            int j = qs - 64 + f * 16 + (l & 15);
            bool valid = (j >= 0) && (j <= i) && (j > i - WIN_);
            sacc[f][r] = valid ? sacc[f][r] * (1.f / 16.f) : -1e9f;
        }
        float mm = -1e30f;
#pragma unroll
        for (int f = 0; f < 8; f++) mm = fmaxf(mm, sacc[f][r]);
        mm = fmaxf(mm, __shfl_xor(mm, 1, 64));
        mm = fmaxf(mm, __shfl_xor(mm, 2, 64));
        mm = fmaxf(mm, __shfl_xor(mm, 4, 64));
        mm = fmaxf(mm, __shfl_xor(mm, 8, 64));
        float ss = 0.f;
#pragma unroll
        for (int f = 0; f < 8; f++) {
            float e = __expf(sacc[f][r] - mm);
            sacc[f][r] = e;
            ss += e;
        }
        ss += __shfl_xor(ss, 1, 64);
        ss += __shfl_xor(ss, 2, 64);
        ss += __shfl_xor(ss, 4, 64);
        ss += __shfl_xor(ss, 8, 64);
        float inv = 1.f / ss;
#pragma unroll
        for (int f = 0; f < 8; f++) sacc[f][r] *= inv;
    }
    __syncthreads();

    bf16(*VT)[72] = (bf16(*)[72])U;
#pragma unroll
    for (int f = 0; f < 8; f++)
#pragma unroll
        for (int r = 0; r < 4; r++)
            Ps[r0 + (l >> 4) * 4 + r][f * 16 + (l & 15)] = __float2bfloat16(sacc[f][r]);
#pragma unroll
    for (int c = 0; c < 8; c++) {
        int col = lc4 + c * 32;
        bf16 tmp[8];
        *(uint4*)tmp = vreg[c];
        for (int e = 0; e < 8; e++) VT[col + e][lrow] = tmp[e];
    }
    __syncthreads();
    {
        const bf16* vrow = XW + (size_t)(b * T_ + qs + lrow) * SX_ + 4096 + h * KD_;
#pragma unroll
        for (int c = 0; c < 8; c++) vreg[c] = *(const uint4*)(vrow + lc4 + c * 32);
    }

    f32x4 oacc[16];
#pragma unroll
    for (int nf = 0; nf < 16; nf++) oacc[nf] = (f32x4){0.f, 0.f, 0.f, 0.f};
    for (int kb = 0; kb < 2; kb++) {
#pragma unroll
        for (int ks = 0; ks < 2; ks++) {
            s16x8 a = *(const s16x8*)&Ps[r0 + (l & 15)][kb * 64 + ks * 32 + (l >> 4) * 8];
            __builtin_amdgcn_s_setprio(1);
#pragma unroll
            for (int nf = 0; nf < 16; nf++) {
                s16x8 bb = *(const s16x8*)&VT[nf * 16 + (l & 15)][ks * 32 + (l >> 4) * 8];
                oacc[nf] = __builtin_amdgcn_mfma_f32_16x16x32_bf16(a, bb, oacc[nf], 0, 0, 0);
            }
            __builtin_amdgcn_s_setprio(0);
        }
        if (kb == 0) {
            __syncthreads();
#pragma unroll
            for (int c = 0; c < 8; c++) {
                int col = lc4 + c * 32;
                bf16 tmp[8];
                *(uint4*)tmp = vreg[c];
                for (int e = 0; e < 8; e++) VT[col + e][lrow] = tmp[e];
            }
            __syncthreads();
        }
    }
#pragma unroll
    for (int nf = 0; nf < 16; nf++)
#pragma unroll
        for (int r = 0; r < 4; r++) {
            int row = r0 + (l >> 4) * 4 + r;
            int col = nf * 16 + (l & 15);
            O[obase + (size_t)(qs + row) * HK_ + col] = __float2bfloat16(oacc[nf][r]);
        }
}

// ---------------- global path ----------------
__global__ __launch_bounds__(256) void qg_kernel(const float* __restrict__ x, const bf16* __restrict__ gwq_t,
                                                 const float* __restrict__ gbq, float* __restrict__ qg) {
    __shared__ float xs[256];
    int bi = blockIdx.x, ch = blockIdx.y, tid = threadIdx.x;
    int b = bi >> 1, i = bi & 1;
    xs[tid] = x[((size_t)b * T_ + (T_ - 2 + i)) * D_ + tid];
    __syncthreads();
    int hk = ch * 256 + tid;
    const bf16* wr = gwq_t + (size_t)hk * D_;
    float acc = gbq[hk];
    for (int c = 0; c < 32; c++) {
        s16x8 wv = *(const s16x8*)&wr[c * 8];
#pragma unroll
        for (int e = 0; e < 8; e++) acc += xs[c * 8 + e] * bs2f(wv[e]);
    }
    qg[(size_t)bi * HK_ + hk] = acc;
}

// scores vs gK (XW offset 6144). grid (B*H, T/256).
__global__ __launch_bounds__(256) void g2_scores(const float* __restrict__ qg, const bf16* __restrict__ XW,
                                                 float* __restrict__ sc) {
    __shared__ float qf[2][256];
    int bh = blockIdx.x, ch = blockIdx.y;
    int b = bh >> 3, h = bh & 7;
    int tid = threadIdx.x;
    for (int i = 0; i < 2; i++)
        qf[i][tid] = qg[(size_t)(b * 2 + i) * HK_ + h * KD_ + tid];
    __syncthreads();
    int t = ch * 256 + tid;
    const bf16* kr = &XW[((size_t)(b * T_ + t)) * SX_ + 6144 + h * KD_];
    float a0 = 0.f, a1 = 0.f;
    for (int c = 0; c < 32; c++) {
        s16x8 kv = *(const s16x8*)&kr[c * 8];
#pragma unroll
        for (int e = 0; e < 8; e++) {
            float kf = bs2f(kv[e]);
            a0 += kf * qf[0][c * 8 + e];
            a1 += kf * qf[1][c * 8 + e];
        }
    }
    sc[((size_t)bh * 2 + 0) * T_ + t] = a0 * (1.f / 16.f);
    sc[((size_t)bh * 2 + 1) * T_ + t] = a1 * (1.f / 16.f);
}

__global__ __launch_bounds__(256) void g2_softmax(float* __restrict__ sc) {
    __shared__ float red[4];
    int bh = blockIdx.x, tid = threadIdx.x;
    int w = tid >> 6;
    for (int i = 0; i < 2; i++) {
        float* row = &sc[((size_t)bh * 2 + i) * T_];
        float vals[4];
        float m = -1e30f;
        for (int c = 0; c < 4; c++) {
            vals[c] = row[tid + 256 * c];
            m = fmaxf(m, vals[c]);
        }
        for (int s = 32; s >= 1; s >>= 1) m = fmaxf(m, __shfl_xor(m, s, 64));
        if ((tid & 63) == 0) red[w] = m;
        __syncthreads();
        m = fmaxf(fmaxf(red[0], red[1]), fmaxf(red[2], red[3]));
        __syncthreads();
        float s = 0.f;
        for (int c = 0; c < 4; c++) {
            vals[c] = __expf(vals[c] - m);
            s += vals[c];
        }
        for (int d = 32; d >= 1; d >>= 1) s += __shfl_xor(s, d, 64);
        if ((tid & 63) == 0) red[w] = s;
        __syncthreads();
        s = red[0] + red[1] + red[2] + red[3];
        float inv = 1.f / s;
        for (int c = 0; c < 4; c++) row[tid + 256 * c] = vals[c] * inv;
        __syncthreads();
    }
}

// PV partial over 256-key chunk (XW offset 8192). grid (B*H, 4).
__global__ __launch_bounds__(256) void g2_pv(const float* __restrict__ sc, const bf16* __restrict__ XW,
                                             float* __restrict__ og_part) {
    __shared__ float p2[2][256];
    int bh = blockIdx.x, ch = blockIdx.y;
    int b = bh >> 3, h = bh & 7;
    int tid = threadIdx.x;
    for (int i = 0; i < 2; i++) p2[i][tid] = sc[((size_t)bh * 2 + i) * T_ + ch * 256 + tid];
    __syncthreads();
    const bf16* vb = &XW[((size_t)(b * T_ + ch * 256)) * SX_ + 8192 + h * KD_ + tid];
    float a0 = 0.f, a1 = 0.f;
    for (int t = 0; t < 256; t++) {
        float vv = b2f(vb[(size_t)t * SX_]);
        a0 += p2[0][t] * vv;
        a1 += p2[1][t] * vv;
    }
    og_part[((size_t)(bh * 4 + ch) * 2 + 0) * KD_ + tid] = a0;
    og_part[((size_t)(bh * 4 + ch) * 2 + 1) * KD_ + tid] = a1;
}

// merged red+lin: g2buf[bi][d] = (reduced og_part)[bi] . gwoT[d] + gbo[d]. grid (16,16).
__global__ __launch_bounds__(256) void g2_lin2(const float* __restrict__ og_part, const bf16* __restrict__ gwoT,
                                               const float* __restrict__ gbo, float* __restrict__ g2buf) {
    __shared__ float og_row[2048];
    int bi = blockIdx.x, tid = threadIdx.x;
    int b = bi >> 1, i = bi & 1;
#pragma unroll
    for (int j = 0; j < 8; j++) {
        int idx = j * 256 + tid;
        int h = idx >> 8, kd = idx & 255;
        int bh = b * 8 + h;
        float s = 0.f;
#pragma unroll
        for (int ch = 0; ch < 4; ch++)
            s += og_part[((size_t)(bh * 4 + ch) * 2 + i) * KD_ + kd];
        og_row[idx] = s;
    }
    __syncthreads();
    int d = blockIdx.y * 16 + (tid >> 4);
    int s16i = tid & 15;
    const float* ogr = og_row + s16i * 128;
    const bf16* wr = gwoT + (size_t)d * HK_ + s16i * 128;
    float acc = 0.f;
    for (int c = 0; c < 16; c++) {
        s16x8 wv = *(const s16x8*)&wr[c * 8];
#pragma unroll
        for (int e = 0; e < 8; e++) acc += ogr[c * 8 + e] * bs2f(wv[e]);
    }
    acc += __shfl_xor(acc, 1, 64);
    acc += __shfl_xor(acc, 2, 64);
    acc += __shfl_xor(acc, 4, 64);
    acc += __shfl_xor(acc, 8, 64);
    if (s16i == 0) g2buf[(size_t)bi * 256 + d] = acc + gbo[d];
}

// merged g2_kv + a2w2: grid (16, 8). Computes K2/V2 head-slice in LDS, then A2/W2/c2.
__global__ __launch_bounds__(256) void g2_kva2(const float* __restrict__ g2buf, const bf16* __restrict__ gwk_t,
                                               const float* __restrict__ gbk, const bf16* __restrict__ gwv_t,
                                               const float* __restrict__ gbv, const bf16* __restrict__ gwq_t,
                                               const bf16* __restrict__ gwoT, const float* __restrict__ gbq,
                                               float* __restrict__ A2, float* __restrict__ W2,
                                               float* __restrict__ c2) {
    __shared__ float g2s[256], k2s[256], v2s[256];
    __shared__ float red[4];
    int bi = blockIdx.x, h = blockIdx.y, tid = threadIdx.x;
    g2s[tid] = g2buf[(size_t)bi * 256 + tid];
    __syncthreads();
    int hk = h * 256 + tid;
    {
        const bf16* rk = &gwk_t[(size_t)hk * D_];
        const bf16* rv = &gwv_t[(size_t)hk * D_];
        float ak = gbk[hk], av = gbv[hk];
        for (int c = 0; c < 32; c++) {
            s16x8 kw = *(const s16x8*)&rk[c * 8];
            s16x8 vw = *(const s16x8*)&rv[c * 8];
#pragma unroll
            for (int e = 0; e < 8; e++) {
                float g = g2s[c * 8 + e];
                ak += g * bs2f(kw[e]);
                av += g * bs2f(vw[e]);
            }
        }
        k2s[tid] = ak;
        v2s[tid] = av;
    }
    __syncthreads();
    float accA = 0.f;
    const bf16* wq = gwq_t + (size_t)(h * 256) * D_ + tid;
    for (int kd = 0; kd < 256; kd++)
        accA += k2s[kd] * b2f(wq[(size_t)kd * D_]);
    float accW = 0.f;
    const bf16* wo = gwoT + (size_t)tid * HK_ + h * 256;
    for (int c = 0; c < 32; c++) {
        s16x8 wv = *(const s16x8*)&wo[c * 8];
#pragma unroll
        for (int e = 0; e < 8; e++) accW += v2s[c * 8 + e] * bs2f(wv[e]);
    }
    int o = (bi * 8 + h) * 256 + tid;
    A2[o] = accA;
    W2[o] = accW;
    float pc = gbq[h * 256 + tid] * k2s[tid];
#pragma unroll
    for (int m = 32; m >= 1; m >>= 1) pc += __shfl_xor(pc, m, 64);
    if ((tid & 63) == 0) red[tid >> 6] = pc;
    __syncthreads();
    if (tid == 0) c2[bi * 8 + h] = red[0] + red[1] + red[2] + red[3];
}

// ---------------- LN1 with inline gx: out1b = LN(x + attnL + gx(x)). grid BT/4, wave/row ----------------
__global__ __launch_bounds__(256) void ln1_gx(const float* __restrict__ x, const bf16* __restrict__ attnL,
                                              const float* __restrict__ A2, const float* __restrict__ W2,
                                              const float* __restrict__ c2, const float* __restrict__ gbo,
                                              const float* __restrict__ g, const float* __restrict__ bia,
                                              bf16* __restrict__ outb) {
    int w = threadIdx.x >> 6, l = threadIdx.x & 63;
    int t = blockIdx.x * 4 + w;
    int b = t >> 10;
    size_t base = (size_t)t * D_ + l * 4;
    float4 x4 = *(const float4*)(x + base);
    // gx: scores via A2 dot x, softmax over 2 keys, combine W2
    float p[8][2];
#pragma unroll
    for (int h = 0; h < 8; h++)
#pragma unroll
        for (int i = 0; i < 2; i++) {
            float4 a4 = *(const float4*)(A2 + ((size_t)((b * 2 + i) * 8 + h)) * 256 + l * 4);
            float dt = x4.x * a4.x + x4.y * a4.y + x4.z * a4.z + x4.w * a4.w;
#pragma unroll
            for (int m = 32; m >= 1; m >>= 1) dt += __shfl_xor(dt, m, 64);
            p[h][i] = dt;
        }
    float4 gb = *(const float4*)(gbo + l * 4);
    float o0 = gb.x, o1 = gb.y, o2 = gb.z, o3 = gb.w;
#pragma unroll
    for (int h = 0; h < 8; h++) {
        float s0 = (p[h][0] + c2[(b * 2 + 0) * 8 + h]) * (1.f / 16.f);
        float s1 = (p[h][1] + c2[(b * 2 + 1) * 8 + h]) * (1.f / 16.f);
        float mx = fmaxf(s0, s1);
        float e0 = __expf(s0 - mx), e1 = __expf(s1 - mx);
        float inv = 1.f / (e0 + e1);
        float p0 = e0 * inv, p1 = e1 * inv;
        float4 w0 = *(const float4*)(W2 + ((size_t)((b * 2 + 0) * 8 + h)) * 256 + l * 4);
        float4 w1 = *(const float4*)(W2 + ((size_t)((b * 2 + 1) * 8 + h)) * 256 + l * 4);
        o0 += p0 * w0.x + p1 * w1.x;
        o1 += p0 * w0.y + p1 * w1.y;
        o2 += p0 * w0.z + p1 * w1.z;
        o3 += p0 * w0.w + p1 * w1.w;
    }
    // v = x + attnL + gx
    ushort4 av = *(const ushort4*)((const unsigned short*)attnL + base);
    float vv[4];
    vv[0] = x4.x + us2f(av.x) + o0;
    vv[1] = x4.y + us2f(av.y) + o1;
    vv[2] = x4.z + us2f(av.z) + o2;
    vv[3] = x4.w + us2f(av.w) + o3;
    float s = vv[0] + vv[1] + vv[2] + vv[3];
#pragma unroll
    for (int m = 32; m >= 1; m >>= 1) s += __shfl_xor(s, m, 64);
    float mean = s * (1.f / 256.f);
    float q = 0.f;
#pragma unroll
    for (int e = 0; e < 4; e++) {
        float d = vv[e] - mean;
        q += d * d;
    }
#pragma unroll
    for (int m = 32; m >= 1; m >>= 1) q += __shfl_xor(q, m, 64);
    float rs = rsqrtf(q * (1.f / 256.f) + 1e-6f);
    float4 gv = *(const float4*)(g + l * 4);
    float4 biv = *(const float4*)(bia + l * 4);
    ushort4 ou;
    ou.x = fbits((vv[0] - mean) * rs * gv.x + biv.x);
    ou.y = fbits((vv[1] - mean) * rs * gv.y + biv.y);
    ou.z = fbits((vv[2] - mean) * rs * gv.z + biv.z);
    ou.w = fbits((vv[3] - mean) * rs * gv.w + biv.w);
    *(ushort4*)((unsigned short*)outb + base) = ou;
}

// ---------------- LayerNorm over D=256: wave per row (LN2) ----------------
template <typename TA, bool HASC>
__global__ __launch_bounds__(256) void ln_kernel(const TA* __restrict__ a, const bf16* __restrict__ b2,
                                                 const bf16* __restrict__ c, const float* __restrict__ g,
                                                 const float* __restrict__ bia, float* __restrict__ outf,
                                                 bf16* __restrict__ outb) {
    int w = threadIdx.x >> 6, l = threadIdx.x & 63;
    int row = blockIdx.x * 4 + w;
    size_t base = (size_t)row * D_ + l * 4;
    float vv[4];
    if constexpr (sizeof(TA) == 4) {
        float4 av = *(const float4*)((const float*)a + base);
        vv[0] = av.x; vv[1] = av.y; vv[2] = av.z; vv[3] = av.w;
    } else {
        ushort4 av = *(const ushort4*)((const unsigned short*)a + base);
        vv[0] = us2f(av.x); vv[1] = us2f(av.y); vv[2] = us2f(av.z); vv[3] = us2f(av.w);
    }
    ushort4 bv = *(const ushort4*)((const unsigned short*)b2 + base);
    vv[0] += us2f(bv.x); vv[1] += us2f(bv.y); vv[2] += us2f(bv.z); vv[3] += us2f(bv.w);
    if constexpr (HASC) {
        ushort4 cv = *(const ushort4*)((const unsigned short*)c + base);
        vv[0] += us2f(cv.x); vv[1] += us2f(cv.y); vv[2] += us2f(cv.z); vv[3] += us2f(cv.w);
    }
    float s = vv[0] + vv[1] + vv[2] + vv[3];
#pragma unroll
    for (int m = 32; m >= 1; m >>= 1) s += __shfl_xor(s, m, 64);
    float mean = s * (1.f / 256.f);
    float q = 0.f;
#pragma unroll
    for (int e = 0; e < 4; e++) {
        float d = vv[e] - mean;
        q += d * d;
    }
#pragma unroll
    for (int m = 32; m >= 1; m >>= 1) q += __shfl_xor(q, m, 64);
    float rs = rsqrtf(q * (1.f / 256.f) + 1e-6f);
    float4 gv = *(const float4*)(g + l * 4);
    float4 biv = *(const float4*)(bia + l * 4);
    float o0 = (vv[0] - mean) * rs * gv.x + biv.x;
    float o1 = (vv[1] - mean) * rs * gv.y + biv.y;
    float o2 = (vv[2] - mean) * rs * gv.z + biv.z;
    float o3 = (vv[3] - mean) * rs * gv.w + biv.w;
    if (outf) *(float4*)(outf + base) = (float4){o0, o1, o2, o3};
    if (outb) {
        ushort4 ou;
        ou.x = fbits(o0); ou.y = fbits(o1); ou.z = fbits(o2); ou.w = fbits(o3);
        *(ushort4*)(outb + base) = ou;
    }
}

extern "C" void kernel_launch(void* const* d_in, const int* in_sizes, int n_in, void* d_out, int out_size,
                              void* d_ws, size_t ws_size, hipStream_t stream) {
    const float* x = (const float*)d_in[0];
    const float* lWq = (const float*)d_in[1];  const float* lbq = (const float*)d_in[2];
    const float* lWk = (const float*)d_in[3];  const float* lbk = (const float*)d_in[4];
    const float* lWv = (const float*)d_in[5];  const float* lbv = (const float*)d_in[6];
    const float* lWo = (const float*)d_in[7];  const float* lbo = (const float*)d_in[8];
    const float* gWq = (const float*)d_in[9];  const float* gbq = (const float*)d_in[10];
    const float* gWk = (const float*)d_in[11]; const float* gbk = (const float*)d_in[12];
    const float* gWv = (const float*)d_in[13]; const float* gbv = (const float*)d_in[14];
    const float* gWo = (const float*)d_in[15]; const float* gbo = (const float*)d_in[16];
    const float* fW1 = (const float*)d_in[17]; const float* fb1 = (const float*)d_in[18];
    const float* fW2 = (const float*)d_in[19]; const float* fb2 = (const float*)d_in[20];
    const float* ln1g = (const float*)d_in[21]; const float* ln1b = (const float*)d_in[22];
    const float* ln2g = (const float*)d_in[23]; const float* ln2b = (const float*)d_in[24];

    char* ws = (char*)d_ws;
    size_t off = 0;
    auto alloc = [&](size_t bytes) -> char* {
        char* p = ws + off;
        off = (off + bytes + 255) & ~(size_t)255;
        return p;
    };
    bf16* xb = (bf16*)alloc((size_t)BT_ * D_ * 2);
    bf16* W10 = (bf16*)alloc((size_t)SX_ * D_ * 2);     // [lWq|lWk|lWv|gWk|gWv]^T
    bf16* gwq_t = (bf16*)alloc((size_t)HK_ * D_ * 2);   // gWq^T
    bf16* woL = (bf16*)alloc((size_t)D_ * HK_ * 2);     // lWo^T
    bf16* gwoT = (bf16*)alloc((size_t)D_ * HK_ * 2);    // gWo^T
    bf16* fw1_t = (bf16*)alloc((size_t)FF_ * D_ * 2);
    bf16* fw2_t = (bf16*)alloc((size_t)D_ * FF_ * 2);
    float* bcat10 = (float*)alloc((size_t)SX_ * 4);
    bf16* XW = (bf16*)alloc((size_t)BT_ * SX_ * 2);     // 160 MB merged projection output
    bf16* Ob = (bf16*)alloc((size_t)BT_ * HK_ * 2);     // 32 MB local attn out
    bf16* attnL = (bf16*)alloc((size_t)BT_ * D_ * 2);
    float* sc = (float*)alloc((size_t)B_ * H_ * 2 * T_ * 4);
    float* og_part = (float*)alloc((size_t)B_ * H_ * 4 * 2 * KD_ * 4);
    float* g2buf = (float*)alloc((size_t)B_ * 2 * D_ * 4);
    float* qg = (float*)alloc((size_t)B_ * 2 * HK_ * 4);
    float* A2 = (float*)alloc((size_t)16 * 8 * 256 * 4);
    float* W2 = (float*)alloc((size_t)16 * 8 * 256 * 4);
    float* c2 = (float*)alloc((size_t)16 * 8 * 4);
    // aliases into XW (fully dead after g2_pv; LN1/FFN run later):
    bf16* hid = XW;                                     // [8192][1024] bf16, 16 MB @ 0
    bf16* ffn = (bf16*)((char*)XW + (32u << 20));       // 4 MB @ 32M
    bf16* out1b = (bf16*)((char*)XW + (48u << 20));     // 4 MB @ 48M

    // 0. convert + transposes + biases + qg
    f32_to_bf16_vec<<<(BT_ * D_) / 1024, 256, 0, stream>>>(x, xb, BT_ * D_);
    {
        TJobs js;
        int t = 0;
        auto add = [&](int i, const float* in, bf16* out, int R, int C, int os) {
            js.j[i] = {in, out, R, C, os, t};
            t += (R / 32) * (C / 32);
        };
        add(0, lWq, W10, D_, HK_, D_);
        add(1, lWk, W10 + (size_t)2048 * D_, D_, HK_, D_);
        add(2, lWv, W10 + (size_t)4096 * D_, D_, HK_, D_);
        add(3, gWk, W10 + (size_t)6144 * D_, D_, HK_, D_);
        add(4, gWv, W10 + (size_t)8192 * D_, D_, HK_, D_);
        add(5, gWq, gwq_t, D_, HK_, D_);
        add(6, lWo, woL, HK_, D_, HK_);
        add(7, gWo, gwoT, HK_, D_, HK_);
        add(8, fW1, fw1_t, D_, FF_, D_);
        add(9, fW2, fw2_t, FF_, D_, FF_);
        js.total = t;
        transpose_all<<<t, dim3(32, 8), 0, stream>>>(js);
    }
    concat_bias10<<<SX_ / 256, 256, 0, stream>>>(lbq, lbk, lbv, gbk, gbv, bcat10);
    qg_kernel<<<dim3(16, 8), 256, 0, stream>>>(x, gwq_t, gbq, qg);

    // 1. single merged projection GEMM: XW = xb @ W10^T + bcat10
    gemm128<1, 128><<<dim3(SX_ / 128, BT_ / 128), 256, 0, stream>>>(xb, W10, bcat10, XW, BT_, SX_, D_);

    // 2. local path
    local_attn<<<dim3(T_ / 64, B_ * H_), 256, 0, stream>>>(XW, Ob);
    gemm128<1, 32><<<dim3(D_ / 32, BT_ / 128), 256, 0, stream>>>(Ob, woL, lbo, attnL, BT_, D_, HK_);

    // 3. global path
    g2_scores<<<dim3(B_ * H_, T_ / 256), 256, 0, stream>>>(qg, XW, sc);
    g2_softmax<<<B_ * H_, 256, 0, stream>>>(sc);
    g2_pv<<<dim3(B_ * H_, 4), 256, 0, stream>>>(sc, XW, og_part);
    g2_lin2<<<dim3(B_ * 2, 16), 256, 0, stream>>>(og_part, gwoT, gbo, g2buf);
    g2_kva2<<<dim3(16, 8), 256, 0, stream>>>(g2buf, W10 + (size_t)6144 * D_, gbk,
                                             W10 + (size_t)8192 * D_, gbv, gwq_t, gwoT, gbq, A2, W2, c2);

    // 4. LN1(+gx) + FFN + LN2
    ln1_gx<<<BT_ / 4, 256, 0, stream>>>(x, attnL, A2, W2, c2, gbo, ln1g, ln1b, out1b);
    gemm128<2, 128><<<dim3(FF_ / 128, BT_ / 128), 256, 0, stream>>>(out1b, fw1_t, fb1, hid, BT_, FF_, D_);
    gemm128<1, 32><<<dim3(D_ / 32, BT_ / 128), 256, 0, stream>>>(hid, fw2_t, fb2, ffn, BT_, D_, FF_);
    ln_kernel<bf16, false><<<BT_ / 4, 256, 0, stream>>>(out1b, ffn, nullptr, ln2g, ln2b, (float*)d_out, nullptr);
}

// Round 13
// 260.398 us; speedup vs baseline: 1.0778x; 1.0778x over previous
//
#include <hip/hip_runtime.h>
#include <hip/hip_bf16.h>

#define B_ 8
#define T_ 1024
#define D_ 256
#define H_ 8
#define KD_ 256
#define HK_ 2048
#define FF_ 1024
#define WIN_ 64
#define BT_ 8192
#define SX_ 10240   // merged projection row: [lQ|lK|lV|gK|gV]

using bf16 = __hip_bfloat16;
typedef float f32x4 __attribute__((ext_vector_type(4)));
typedef short s16x8 __attribute__((ext_vector_type(8)));

__device__ inline float b2f(bf16 h) { return __bfloat162float(h); }
__device__ inline float bs2f(short s) {
    unsigned int u = ((unsigned int)(unsigned short)s) << 16;
    return __builtin_bit_cast(float, u);
}
__device__ inline float us2f(unsigned short s) {
    unsigned int u = ((unsigned int)s) << 16;
    return __builtin_bit_cast(float, u);
}
__device__ inline unsigned short fbits(float x) { bf16 h = __float2bfloat16(x); return __builtin_bit_cast(unsigned short, h); }

// async global->LDS, 16B per lane; lds base wave-uniform, lane l lands at base + l*16
__device__ __forceinline__ void stage16(const void* g, void* l) {
    __builtin_amdgcn_global_load_lds((const __attribute__((address_space(1))) void*)g,
                                     (__attribute__((address_space(3))) void*)l, 16, 0, 0);
}

// ---------------- elementwise f32 -> bf16 ----------------
__global__ __launch_bounds__(256) void f32_to_bf16_vec(const float* __restrict__ in, bf16* __restrict__ out, int n) {
    int i = (blockIdx.x * 256 + threadIdx.x) * 4;
    if (i + 3 < n) {
        float4 v = *(const float4*)(in + i);
        ushort4 o;
        o.x = fbits(v.x); o.y = fbits(v.y); o.z = fbits(v.z); o.w = fbits(v.w);
        *(ushort4*)(out + i) = o;
    }
}

// ---------------- fused weight transposes: in f32[R][C] -> out bf16[C][R], row stride os ----------------
struct TJob { const float* in; bf16* out; int R; int C; int os; int tile_start; };
struct TJobs { TJob j[10]; int total; };

__global__ void transpose_all(TJobs js) {
    __shared__ float tile[32][33];
    int bid = blockIdx.x;
    int ji = 0;
    while (ji < 9 && bid >= js.j[ji + 1].tile_start) ji++;
    TJob jb = js.j[ji];
    int t = bid - jb.tile_start;
    int tiles_x = jb.C / 32;
    int cb = (t % tiles_x) * 32, rb = (t / tiles_x) * 32;
    for (int k = 0; k < 4; k++) {
        int r = threadIdx.y + k * 8;
        tile[r][threadIdx.x] = jb.in[(size_t)(rb + r) * jb.C + cb + threadIdx.x];
    }
    __syncthreads();
    for (int k = 0; k < 4; k++) {
        int r = threadIdx.y + k * 8;
        jb.out[(size_t)(cb + r) * jb.os + rb + threadIdx.x] = __float2bfloat16(tile[threadIdx.x][r]);
    }
}

// bias concat: bcat10[10240] = [lbq | lbk | lbv | gbk | gbv]
__global__ __launch_bounds__(256) void concat_bias10(const float* a0, const float* a1, const float* a2,
                                                     const float* a3, const float* a4, float* out) {
    int i = blockIdx.x * 256 + threadIdx.x;
    int seg = i >> 11, off = i & 2047;
    const float* p = seg == 0 ? a0 : seg == 1 ? a1 : seg == 2 ? a2 : seg == 3 ? a3 : a4;
    out[i] = p[off];
}

// ---------------- dbuf 2-phase GEMM with T2 LDS swizzle (proven round-9/11) ----------------
// C[M][N] = A[M][K] * Bt[N][K]^T + bias. 128xBN tile, BK=64, 4 waves. bf16 out.
// MODE 1: plain; MODE 2: relu.
template <int MODE, int BN>
__global__ __launch_bounds__(256) void gemm128(const bf16* __restrict__ A, const bf16* __restrict__ Bt,
                                               const float* __restrict__ bias, bf16* __restrict__ C,
                                               int M, int N, int K) {
    constexpr int NF = BN / 32;
    constexpr int ABUF = 128 * 64;
    constexpr int BBUF = BN * 64;
    constexpr int BUFE = ABUF + BBUF;
    constexpr int EC = BN + 8;
    constexpr int ARENA_E = (2 * BUFE > 128 * EC) ? 2 * BUFE : 128 * EC;
    __shared__ __align__(16) bf16 arena[ARENA_E];
    const int tid = threadIdx.x;
    const int w = tid >> 6, l = tid & 63;
    const int m0 = blockIdx.y * 128, n0 = blockIdx.x * BN;
    const int wm = (w >> 1) * 64, wn = (w & 1) * (BN / 2);
    const int srow = w * 8 + (l >> 3);
    const int scol = ((l & 7) ^ (l >> 3)) * 8;   // T2: pre-swizzled source column
    const int ldsOff = w * 512;
    const int nt = K / 64;

    auto stageT = [&](int buf, int k0) {
        bf16* Ad = arena + buf * BUFE;
        bf16* Bd = Ad + ABUF;
#pragma unroll
        for (int j = 0; j < 4; j++)
            stage16(A + (size_t)(m0 + j * 32 + srow) * K + k0 + scol, &Ad[ldsOff + j * 2048]);
#pragma unroll
        for (int j = 0; j < NF; j++)
            stage16(Bt + (size_t)(n0 + j * 32 + srow) * K + k0 + scol, &Bd[ldsOff + j * 2048]);
    };

    f32x4 acc[4][NF] = {};
    stageT(0, 0);
    __syncthreads();
    int cur = 0;
    for (int t = 0; t < nt; t++) {
        if (t + 1 < nt) stageT(cur ^ 1, (t + 1) * 64);
        const bf16* As = arena + cur * BUFE;
        const bf16* Bs = As + ABUF;
#pragma unroll
        for (int ks = 0; ks < 2; ks++) {
            s16x8 a[4], b[NF];
#pragma unroll
            for (int mf = 0; mf < 4; mf++) {
                int ar = wm + mf * 16 + (l & 15);
                int ch = (ks * 4 + (l >> 4)) ^ (ar & 7);
                a[mf] = *(const s16x8*)&As[ar * 64 + ch * 8];
            }
#pragma unroll
            for (int nf = 0; nf < NF; nf++) {
                int br = wn + nf * 16 + (l & 15);
                int ch = (ks * 4 + (l >> 4)) ^ (br & 7);
                b[nf] = *(const s16x8*)&Bs[br * 64 + ch * 8];
            }
            __builtin_amdgcn_s_setprio(1);
#pragma unroll
            for (int mf = 0; mf < 4; mf++)
#pragma unroll
                for (int nf = 0; nf < NF; nf++)
                    acc[mf][nf] = __builtin_amdgcn_mfma_f32_16x16x32_bf16(a[mf], b[nf], acc[mf][nf], 0, 0, 0);
            __builtin_amdgcn_s_setprio(0);
        }
        __syncthreads();
        cur ^= 1;
    }
    bf16* Es = arena;
#pragma unroll
    for (int mf = 0; mf < 4; mf++)
#pragma unroll
        for (int nf = 0; nf < NF; nf++)
#pragma unroll
            for (int r = 0; r < 4; r++) {
                int row = wm + mf * 16 + (l >> 4) * 4 + r;
                int col = wn + nf * 16 + (l & 15);
                float v = acc[mf][nf][r] + bias[n0 + col];
                if (MODE == 2) v = fmaxf(v, 0.f);
                Es[row * EC + col] = __float2bfloat16(v);
            }
    __syncthreads();
    constexpr int RPC = BN / 8;
    constexpr int CPT = (128 * BN) / (256 * 8);
#pragma unroll
    for (int c = 0; c < CPT; c++) {
        int lin = c * 256 + tid;
        int row = lin / RPC, cc = lin - row * RPC;
        s16x8 v = *(const s16x8*)&Es[row * EC + cc * 8];
        *(s16x8*)(C + (size_t)(m0 + row) * N + n0 + cc * 8) = v;
    }
}

// ---------------- local windowed attention (proven; XW stride) ----------------
__global__ __launch_bounds__(256) void local_attn(const bf16* __restrict__ XW, bf16* __restrict__ O) {
    __shared__ bf16 U[256 * 72];
    __shared__ bf16 Ps[64][136];
    const int tid = threadIdx.x, l = tid & 63, w = tid >> 6;
    const int qt = blockIdx.x, bh = blockIdx.y;
    const int b = bh >> 3, h = bh & 7;
    const int qs = qt * 64;
    const int r0 = w * 16;
    const int lrow = tid >> 2, lc4 = (tid & 3) * 8;
    const size_t obase = (size_t)b * T_ * HK_ + h * KD_;

    s16x8 qa[8];
    {
        const bf16* qbase = XW + (size_t)(b * T_ + qs + r0 + (l & 15)) * SX_ + h * KD_ + (l >> 4) * 8;
#pragma unroll
        for (int ks = 0; ks < 8; ks++) qa[ks] = *(const s16x8*)(qbase + ks * 32);
    }

    bf16(*Ks)[264] = (bf16(*)[264])U;
    {
        int tk = qs - 64 + lrow;
        const bf16* krow = XW + (size_t)(b * T_ + tk) * SX_ + 2048 + h * KD_;
#pragma unroll
        for (int c = 0; c < 8; c++) {
            int col = lc4 + c * 32;
            uint4 val = {0, 0, 0, 0};
            if (tk >= 0) val = *(const uint4*)(krow + col);
            *(uint4*)&Ks[lrow][col] = val;
        }
    }
    __syncthreads();
    f32x4 sacc[8];
#pragma unroll
    for (int f = 0; f < 8; f++) sacc[f] = (f32x4){0.f, 0.f, 0.f, 0.f};
    __builtin_amdgcn_s_setprio(1);
#pragma unroll
    for (int nf = 0; nf < 4; nf++)
#pragma unroll
        for (int ks = 0; ks < 8; ks++) {
            s16x8 bb = *(const s16x8*)&Ks[nf * 16 + (l & 15)][ks * 32 + (l >> 4) * 8];
            sacc[nf] = __builtin_amdgcn_mfma_f32_16x16x32_bf16(qa[ks], bb, sacc[nf], 0, 0, 0);
        }
    __builtin_amdgcn_s_setprio(0);
    __syncthreads();
    {
        const bf16* krow = XW + (size_t)(b * T_ + qs + lrow) * SX_ + 2048 + h * KD_;
#pragma unroll
        for (int c = 0; c < 8; c++) {
            int col = lc4 + c * 32;
            *(uint4*)&Ks[lrow][col] = *(const uint4*)(krow + col);
        }
    }
    __syncthreads();
    __builtin_amdgcn_s_setprio(1);
#pragma unroll
    for (int nf = 0; nf < 4; nf++)
#pragma unroll
        for (int ks = 0; ks < 8; ks++) {
            s16x8 bb = *(const s16x8*)&Ks[nf * 16 + (l & 15)][ks * 32 + (l >> 4) * 8];
            sacc[4 + nf] = __builtin_amdgcn_mfma_f32_16x16x32_bf16(qa[ks], bb, sacc[4 + nf], 0, 0, 0);
        }
    __builtin_amdgcn_s_setprio(0);

    uint4 vreg[8];
    {
        int tk = qs - 64 + lrow;
        const bf16* vrow = XW + (size_t)(b * T_ + tk) * SX_ + 4096 + h * KD_;
#pragma unroll
        for (int c = 0; c < 8; c++) {
            uint4 v = {0, 0, 0, 0};
            if (tk >= 0) v = *(const uint4*)(vrow + lc4 + c * 32);
            vreg[c] = v;
        }
    }

#pragma unroll
    for (int r = 0; r < 4; r++) {
        int i = qs + r0 + (l >> 4) * 4 + r;
#pragma unroll
        for (int f = 0; f < 8; f++) {
            int j = qs - 64 + f * 16 + (l & 15);
            bool valid = (j >= 0) && (j <= i) && (j > i - WIN_);
            sacc[f][r] = valid ? sacc[f][r] * (1.f / 16.f) : -1e9f;
        }
        float mm = -1e30f;
#pragma unroll
        for (int f = 0; f < 8; f++) mm = fmaxf(mm, sacc[f][r]);
        mm = fmaxf(mm, __shfl_xor(mm, 1, 64));
        mm = fmaxf(mm, __shfl_xor(mm, 2, 64));
        mm = fmaxf(mm, __shfl_xor(mm, 4, 64));
        mm = fmaxf(mm, __shfl_xor(mm, 8, 64));
        float ss = 0.f;
#pragma unroll
        for (int f = 0; f < 8; f++) {
            float e = __expf(sacc[f][r] - mm);
            sacc[f][r] = e;
            ss += e;
        }
        ss += __shfl_xor(ss, 1, 64);
        ss += __shfl_xor(ss, 2, 64);
        ss += __shfl_xor(ss, 4, 64);
        ss += __shfl_xor(ss, 8, 64);
        float inv = 1.f / ss;
#pragma unroll
        for (int f = 0; f < 8; f++) sacc[f][r] *= inv;
    }
    __syncthreads();

    bf16(*VT)[72] = (bf16(*)[72])U;
#pragma unroll
    for (int f = 0; f < 8; f++)
#pragma unroll
        for (int r = 0; r < 4; r++)
            Ps[r0 + (l >> 4) * 4 + r][f * 16 + (l & 15)] = __float2bfloat16(sacc[f][r]);
#pragma unroll
    for (int c = 0; c < 8; c++) {
        int col = lc4 + c * 32;
        bf16 tmp[8];
        *(uint4*)tmp = vreg[c];
        for (int e = 0; e < 8; e++) VT[col + e][lrow] = tmp[e];
    }
    __syncthreads();
    {
        const bf16* vrow = XW + (size_t)(b * T_ + qs + lrow) * SX_ + 4096 + h * KD_;
#pragma unroll
        for (int c = 0; c < 8; c++) vreg[c] = *(const uint4*)(vrow + lc4 + c * 32);
    }

    f32x4 oacc[16];
#pragma unroll
    for (int nf = 0; nf < 16; nf++) oacc[nf] = (f32x4){0.f, 0.f, 0.f, 0.f};
    for (int kb = 0; kb < 2; kb++) {
#pragma unroll
        for (int ks = 0; ks < 2; ks++) {
            s16x8 a = *(const s16x8*)&Ps[r0 + (l & 15)][kb * 64 + ks * 32 + (l >> 4) * 8];
            __builtin_amdgcn_s_setprio(1);
#pragma unroll
            for (int nf = 0; nf < 16; nf++) {
                s16x8 bb = *(const s16x8*)&VT[nf * 16 + (l & 15)][ks * 32 + (l >> 4) * 8];
                oacc[nf] = __builtin_amdgcn_mfma_f32_16x16x32_bf16(a, bb, oacc[nf], 0, 0, 0);
            }
            __builtin_amdgcn_s_setprio(0);
        }
        if (kb == 0) {
            __syncthreads();
#pragma unroll
            for (int c = 0; c < 8; c++) {
                int col = lc4 + c * 32;
                bf16 tmp[8];
                *(uint4*)tmp = vreg[c];
                for (int e = 0; e < 8; e++) VT[col + e][lrow] = tmp[e];
            }
            __syncthreads();
        }
    }
#pragma unroll
    for (int nf = 0; nf < 16; nf++)
#pragma unroll
        for (int r = 0; r < 4; r++) {
            int row = r0 + (l >> 4) * 4 + r;
            int col = nf * 16 + (l & 15);
            O[obase + (size_t)(qs + row) * HK_ + col] = __float2bfloat16(oacc[nf][r]);
        }
}

// ---------------- global path ----------------
__global__ __launch_bounds__(256) void qg_kernel(const float* __restrict__ x, const bf16* __restrict__ gwq_t,
                                                 const float* __restrict__ gbq, float* __restrict__ qg) {
    __shared__ float xs[256];
    int bi = blockIdx.x, ch = blockIdx.y, tid = threadIdx.x;
    int b = bi >> 1, i = bi & 1;
    xs[tid] = x[((size_t)b * T_ + (T_ - 2 + i)) * D_ + tid];
    __syncthreads();
    int hk = ch * 256 + tid;
    const bf16* wr = gwq_t + (size_t)hk * D_;
    float acc = gbq[hk];
    for (int c = 0; c < 32; c++) {
        s16x8 wv = *(const s16x8*)&wr[c * 8];
#pragma unroll
        for (int e = 0; e < 8; e++) acc += xs[c * 8 + e] * bs2f(wv[e]);
    }
    qg[(size_t)bi * HK_ + hk] = acc;
}

// scores vs gK (XW offset 6144). grid (B*H, T/256).
__global__ __launch_bounds__(256) void g2_scores(const float* __restrict__ qg, const bf16* __restrict__ XW,
                                                 float* __restrict__ sc) {
    __shared__ float qf[2][256];
    int bh = blockIdx.x, ch = blockIdx.y;
    int b = bh >> 3, h = bh & 7;
    int tid = threadIdx.x;
    for (int i = 0; i < 2; i++)
        qf[i][tid] = qg[(size_t)(b * 2 + i) * HK_ + h * KD_ + tid];
    __syncthreads();
    int t = ch * 256 + tid;
    const bf16* kr = &XW[((size_t)(b * T_ + t)) * SX_ + 6144 + h * KD_];
    float a0 = 0.f, a1 = 0.f;
    for (int c = 0; c < 32; c++) {
        s16x8 kv = *(const s16x8*)&kr[c * 8];
#pragma unroll
        for (int e = 0; e < 8; e++) {
            float kf = bs2f(kv[e]);
            a0 += kf * qf[0][c * 8 + e];
            a1 += kf * qf[1][c * 8 + e];
        }
    }
    sc[((size_t)bh * 2 + 0) * T_ + t] = a0 * (1.f / 16.f);
    sc[((size_t)bh * 2 + 1) * T_ + t] = a1 * (1.f / 16.f);
}

__global__ __launch_bounds__(256) void g2_softmax(float* __restrict__ sc) {
    __shared__ float red[4];
    int bh = blockIdx.x, tid = threadIdx.x;
    int w = tid >> 6;
    for (int i = 0; i < 2; i++) {
        float* row = &sc[((size_t)bh * 2 + i) * T_];
        float vals[4];
        float m = -1e30f;
        for (int c = 0; c < 4; c++) {
            vals[c] = row[tid + 256 * c];
            m = fmaxf(m, vals[c]);
        }
        for (int s = 32; s >= 1; s >>= 1) m = fmaxf(m, __shfl_xor(m, s, 64));
        if ((tid & 63) == 0) red[w] = m;
        __syncthreads();
        m = fmaxf(fmaxf(red[0], red[1]), fmaxf(red[2], red[3]));
        __syncthreads();
        float s = 0.f;
        for (int c = 0; c < 4; c++) {
            vals[c] = __expf(vals[c] - m);
            s += vals[c];
        }
        for (int d = 32; d >= 1; d >>= 1) s += __shfl_xor(s, d, 64);
        if ((tid & 63) == 0) red[w] = s;
        __syncthreads();
        s = red[0] + red[1] + red[2] + red[3];
        float inv = 1.f / s;
        for (int c = 0; c < 4; c++) row[tid + 256 * c] = vals[c] * inv;
        __syncthreads();
    }
}

// PV partial over 256-key chunk (XW offset 8192). grid (B*H, 4).
__global__ __launch_bounds__(256) void g2_pv(const float* __restrict__ sc, const bf16* __restrict__ XW,
                                             float* __restrict__ og_part) {
    __shared__ float p2[2][256];
    int bh = blockIdx.x, ch = blockIdx.y;
    int b = bh >> 3, h = bh & 7;
    int tid = threadIdx.x;
    for (int i = 0; i < 2; i++) p2[i][tid] = sc[((size_t)bh * 2 + i) * T_ + ch * 256 + tid];
    __syncthreads();
    const bf16* vb = &XW[((size_t)(b * T_ + ch * 256)) * SX_ + 8192 + h * KD_ + tid];
    float a0 = 0.f, a1 = 0.f;
    for (int t = 0; t < 256; t++) {
        float vv = b2f(vb[(size_t)t * SX_]);
        a0 += p2[0][t] * vv;
        a1 += p2[1][t] * vv;
    }
    og_part[((size_t)(bh * 4 + ch) * 2 + 0) * KD_ + tid] = a0;
    og_part[((size_t)(bh * 4 + ch) * 2 + 1) * KD_ + tid] = a1;
}

// merged red+lin: g2buf[bi][d] = (reduced og_part)[bi] . gwoT[d] + gbo[d]. grid (16,16).
__global__ __launch_bounds__(256) void g2_lin2(const float* __restrict__ og_part, const bf16* __restrict__ gwoT,
                                               const float* __restrict__ gbo, float* __restrict__ g2buf) {
    __shared__ float og_row[2048];
    int bi = blockIdx.x, tid = threadIdx.x;
    int b = bi >> 1, i = bi & 1;
#pragma unroll
    for (int j = 0; j < 8; j++) {
        int idx = j * 256 + tid;
        int h = idx >> 8, kd = idx & 255;
        int bh = b * 8 + h;
        float s = 0.f;
#pragma unroll
        for (int ch = 0; ch < 4; ch++)
            s += og_part[((size_t)(bh * 4 + ch) * 2 + i) * KD_ + kd];
        og_row[idx] = s;
    }
    __syncthreads();
    int d = blockIdx.y * 16 + (tid >> 4);
    int s16i = tid & 15;
    const float* ogr = og_row + s16i * 128;
    const bf16* wr = gwoT + (size_t)d * HK_ + s16i * 128;
    float acc = 0.f;
    for (int c = 0; c < 16; c++) {
        s16x8 wv = *(const s16x8*)&wr[c * 8];
#pragma unroll
        for (int e = 0; e < 8; e++) acc += ogr[c * 8 + e] * bs2f(wv[e]);
    }
    acc += __shfl_xor(acc, 1, 64);
    acc += __shfl_xor(acc, 2, 64);
    acc += __shfl_xor(acc, 4, 64);
    acc += __shfl_xor(acc, 8, 64);
    if (s16i == 0) g2buf[(size_t)bi * 256 + d] = acc + gbo[d];
}

// merged g2_kv + a2w2: grid (16, 8). Computes K2/V2 head-slice in LDS, then A2/W2/c2.
__global__ __launch_bounds__(256) void g2_kva2(const float* __restrict__ g2buf, const bf16* __restrict__ gwk_t,
                                               const float* __restrict__ gbk, const bf16* __restrict__ gwv_t,
                                               const float* __restrict__ gbv, const bf16* __restrict__ gwq_t,
                                               const bf16* __restrict__ gwoT, const float* __restrict__ gbq,
                                               float* __restrict__ A2, float* __restrict__ W2,
                                               float* __restrict__ c2) {
    __shared__ float g2s[256], k2s[256], v2s[256];
    __shared__ float red[4];
    int bi = blockIdx.x, h = blockIdx.y, tid = threadIdx.x;
    g2s[tid] = g2buf[(size_t)bi * 256 + tid];
    __syncthreads();
    int hk = h * 256 + tid;
    {
        const bf16* rk = &gwk_t[(size_t)hk * D_];
        const bf16* rv = &gwv_t[(size_t)hk * D_];
        float ak = gbk[hk], av = gbv[hk];
        for (int c = 0; c < 32; c++) {
            s16x8 kw = *(const s16x8*)&rk[c * 8];
            s16x8 vw = *(const s16x8*)&rv[c * 8];
#pragma unroll
            for (int e = 0; e < 8; e++) {
                float g = g2s[c * 8 + e];
                ak += g * bs2f(kw[e]);
                av += g * bs2f(vw[e]);
            }
        }
        k2s[tid] = ak;
        v2s[tid] = av;
    }
    __syncthreads();
    float accA = 0.f;
    const bf16* wq = gwq_t + (size_t)(h * 256) * D_ + tid;
    for (int kd = 0; kd < 256; kd++)
        accA += k2s[kd] * b2f(wq[(size_t)kd * D_]);
    float accW = 0.f;
    const bf16* wo = gwoT + (size_t)tid * HK_ + h * 256;
    for (int c = 0; c < 32; c++) {
        s16x8 wv = *(const s16x8*)&wo[c * 8];
#pragma unroll
        for (int e = 0; e < 8; e++) accW += v2s[c * 8 + e] * bs2f(wv[e]);
    }
    int o = (bi * 8 + h) * 256 + tid;
    A2[o] = accA;
    W2[o] = accW;
    float pc = gbq[h * 256 + tid] * k2s[tid];
#pragma unroll
    for (int m = 32; m >= 1; m >>= 1) pc += __shfl_xor(pc, m, 64);
    if ((tid & 63) == 0) red[tid >> 6] = pc;
    __syncthreads();
    if (tid == 0) c2[bi * 8 + h] = red[0] + red[1] + red[2] + red[3];
}

// ---------------- LN1 with inline gx: out1b = LN(x + attnL + gx(x)). grid BT/4, wave/row ----------------
__global__ __launch_bounds__(256) void ln1_gx(const float* __restrict__ x, const bf16* __restrict__ attnL,
                                              const float* __restrict__ A2, const float* __restrict__ W2,
                                              const float* __restrict__ c2, const float* __restrict__ gbo,
                                              const float* __restrict__ g, const float* __restrict__ bia,
                                              bf16* __restrict__ outb) {
    int w = threadIdx.x >> 6, l = threadIdx.x & 63;
    int t = blockIdx.x * 4 + w;
    int b = t >> 10;
    size_t base = (size_t)t * D_ + l * 4;
    float4 x4 = *(const float4*)(x + base);
    float p[8][2];
#pragma unroll
    for (int h = 0; h < 8; h++)
#pragma unroll
        for (int i = 0; i < 2; i++) {
            float4 a4 = *(const float4*)(A2 + ((size_t)((b * 2 + i) * 8 + h)) * 256 + l * 4);
            float dt = x4.x * a4.x + x4.y * a4.y + x4.z * a4.z + x4.w * a4.w;
#pragma unroll
            for (int m = 32; m >= 1; m >>= 1) dt += __shfl_xor(dt, m, 64);
            p[h][i] = dt;
        }
    float4 gb = *(const float4*)(gbo + l * 4);
    float o0 = gb.x, o1 = gb.y, o2 = gb.z, o3 = gb.w;
#pragma unroll
    for (int h = 0; h < 8; h++) {
        float s0 = (p[h][0] + c2[(b * 2 + 0) * 8 + h]) * (1.f / 16.f);
        float s1 = (p[h][1] + c2[(b * 2 + 1) * 8 + h]) * (1.f / 16.f);
        float mx = fmaxf(s0, s1);
        float e0 = __expf(s0 - mx), e1 = __expf(s1 - mx);
        float inv = 1.f / (e0 + e1);
        float p0 = e0 * inv, p1 = e1 * inv;
        float4 w0 = *(const float4*)(W2 + ((size_t)((b * 2 + 0) * 8 + h)) * 256 + l * 4);
        float4 w1 = *(const float4*)(W2 + ((size_t)((b * 2 + 1) * 8 + h)) * 256 + l * 4);
        o0 += p0 * w0.x + p1 * w1.x;
        o1 += p0 * w0.y + p1 * w1.y;
        o2 += p0 * w0.z + p1 * w1.z;
        o3 += p0 * w0.w + p1 * w1.w;
    }
    ushort4 av = *(const ushort4*)((const unsigned short*)attnL + base);
    float vv[4];
    vv[0] = x4.x + us2f(av.x) + o0;
    vv[1] = x4.y + us2f(av.y) + o1;
    vv[2] = x4.z + us2f(av.z) + o2;
    vv[3] = x4.w + us2f(av.w) + o3;
    float s = vv[0] + vv[1] + vv[2] + vv[3];
#pragma unroll
    for (int m = 32; m >= 1; m >>= 1) s += __shfl_xor(s, m, 64);
    float mean = s * (1.f / 256.f);
    float q = 0.f;
#pragma unroll
    for (int e = 0; e < 4; e++) {
        float d = vv[e] - mean;
        q += d * d;
    }
#pragma unroll
    for (int m = 32; m >= 1; m >>= 1) q += __shfl_xor(q, m, 64);
    float rs = rsqrtf(q * (1.f / 256.f) + 1e-6f);
    float4 gv = *(const float4*)(g + l * 4);
    float4 biv = *(const float4*)(bia + l * 4);
    ushort4 ou;
    ou.x = fbits((vv[0] - mean) * rs * gv.x + biv.x);
    ou.y = fbits((vv[1] - mean) * rs * gv.y + biv.y);
    ou.z = fbits((vv[2] - mean) * rs * gv.z + biv.z);
    ou.w = fbits((vv[3] - mean) * rs * gv.w + biv.w);
    *(ushort4*)((unsigned short*)outb + base) = ou;
}

// ---------------- LayerNorm over D=256: wave per row (LN2) ----------------
template <typename TA, bool HASC>
__global__ __launch_bounds__(256) void ln_kernel(const TA* __restrict__ a, const bf16* __restrict__ b2,
                                                 const bf16* __restrict__ c, const float* __restrict__ g,
                                                 const float* __restrict__ bia, float* __restrict__ outf,
                                                 bf16* __restrict__ outb) {
    int w = threadIdx.x >> 6, l = threadIdx.x & 63;
    int row = blockIdx.x * 4 + w;
    size_t base = (size_t)row * D_ + l * 4;
    float vv[4];
    if constexpr (sizeof(TA) == 4) {
        float4 av = *(const float4*)((const float*)a + base);
        vv[0] = av.x; vv[1] = av.y; vv[2] = av.z; vv[3] = av.w;
    } else {
        ushort4 av = *(const ushort4*)((const unsigned short*)a + base);
        vv[0] = us2f(av.x); vv[1] = us2f(av.y); vv[2] = us2f(av.z); vv[3] = us2f(av.w);
    }
    ushort4 bv = *(const ushort4*)((const unsigned short*)b2 + base);
    vv[0] += us2f(bv.x); vv[1] += us2f(bv.y); vv[2] += us2f(bv.z); vv[3] += us2f(bv.w);
    if constexpr (HASC) {
        ushort4 cv = *(const ushort4*)((const unsigned short*)c + base);
        vv[0] += us2f(cv.x); vv[1] += us2f(cv.y); vv[2] += us2f(cv.z); vv[3] += us2f(cv.w);
    }
    float s = vv[0] + vv[1] + vv[2] + vv[3];
#pragma unroll
    for (int m = 32; m >= 1; m >>= 1) s += __shfl_xor(s, m, 64);
    float mean = s * (1.f / 256.f);
    float q = 0.f;
#pragma unroll
    for (int e = 0; e < 4; e++) {
        float d = vv[e] - mean;
        q += d * d;
    }
#pragma unroll
    for (int m = 32; m >= 1; m >>= 1) q += __shfl_xor(q, m, 64);
    float rs = rsqrtf(q * (1.f / 256.f) + 1e-6f);
    float4 gv = *(const float4*)(g + l * 4);
    float4 biv = *(const float4*)(bia + l * 4);
    float o0 = (vv[0] - mean) * rs * gv.x + biv.x;
    float o1 = (vv[1] - mean) * rs * gv.y + biv.y;
    float o2 = (vv[2] - mean) * rs * gv.z + biv.z;
    float o3 = (vv[3] - mean) * rs * gv.w + biv.w;
    if (outf) *(float4*)(outf + base) = (float4){o0, o1, o2, o3};
    if (outb) {
        ushort4 ou;
        ou.x = fbits(o0); ou.y = fbits(o1); ou.z = fbits(o2); ou.w = fbits(o3);
        *(ushort4*)(outb + base) = ou;
    }
}

extern "C" void kernel_launch(void* const* d_in, const int* in_sizes, int n_in, void* d_out, int out_size,
                              void* d_ws, size_t ws_size, hipStream_t stream) {
    const float* x = (const float*)d_in[0];
    const float* lWq = (const float*)d_in[1];  const float* lbq = (const float*)d_in[2];
    const float* lWk = (const float*)d_in[3];  const float* lbk = (const float*)d_in[4];
    const float* lWv = (const float*)d_in[5];  const float* lbv = (const float*)d_in[6];
    const float* lWo = (const float*)d_in[7];  const float* lbo = (const float*)d_in[8];
    const float* gWq = (const float*)d_in[9];  const float* gbq = (const float*)d_in[10];
    const float* gWk = (const float*)d_in[11]; const float* gbk = (const float*)d_in[12];
    const float* gWv = (const float*)d_in[13]; const float* gbv = (const float*)d_in[14];
    const float* gWo = (const float*)d_in[15]; const float* gbo = (const float*)d_in[16];
    const float* fW1 = (const float*)d_in[17]; const float* fb1 = (const float*)d_in[18];
    const float* fW2 = (const float*)d_in[19]; const float* fb2 = (const float*)d_in[20];
    const float* ln1g = (const float*)d_in[21]; const float* ln1b = (const float*)d_in[22];
    const float* ln2g = (const float*)d_in[23]; const float* ln2b = (const float*)d_in[24];

    char* ws = (char*)d_ws;
    size_t off = 0;
    auto alloc = [&](size_t bytes) -> char* {
        char* p = ws + off;
        off = (off + bytes + 255) & ~(size_t)255;
        return p;
    };
    bf16* xb = (bf16*)alloc((size_t)BT_ * D_ * 2);
    bf16* W10 = (bf16*)alloc((size_t)SX_ * D_ * 2);     // [lWq|lWk|lWv|gWk|gWv]^T
    bf16* gwq_t = (bf16*)alloc((size_t)HK_ * D_ * 2);   // gWq^T
    bf16* woL = (bf16*)alloc((size_t)D_ * HK_ * 2);     // lWo^T
    bf16* gwoT = (bf16*)alloc((size_t)D_ * HK_ * 2);    // gWo^T
    bf16* fw1_t = (bf16*)alloc((size_t)FF_ * D_ * 2);
    bf16* fw2_t = (bf16*)alloc((size_t)D_ * FF_ * 2);
    float* bcat10 = (float*)alloc((size_t)SX_ * 4);
    bf16* XW = (bf16*)alloc((size_t)BT_ * SX_ * 2);     // 160 MB merged projection output
    bf16* Ob = (bf16*)alloc((size_t)BT_ * HK_ * 2);     // 32 MB local attn out
    bf16* attnL = (bf16*)alloc((size_t)BT_ * D_ * 2);
    float* sc = (float*)alloc((size_t)B_ * H_ * 2 * T_ * 4);
    float* og_part = (float*)alloc((size_t)B_ * H_ * 4 * 2 * KD_ * 4);
    float* g2buf = (float*)alloc((size_t)B_ * 2 * D_ * 4);
    float* qg = (float*)alloc((size_t)B_ * 2 * HK_ * 4);
    float* A2 = (float*)alloc((size_t)16 * 8 * 256 * 4);
    float* W2 = (float*)alloc((size_t)16 * 8 * 256 * 4);
    float* c2 = (float*)alloc((size_t)16 * 8 * 4);
    // aliases into XW (fully dead after g2_pv; LN1/FFN run later):
    bf16* hid = XW;                                     // [8192][1024] bf16, 16 MB @ 0
    bf16* ffn = (bf16*)((char*)XW + (32u << 20));       // 4 MB @ 32M
    bf16* out1b = (bf16*)((char*)XW + (48u << 20));     // 4 MB @ 48M

    // 0. convert + transposes + biases + qg
    f32_to_bf16_vec<<<(BT_ * D_) / 1024, 256, 0, stream>>>(x, xb, BT_ * D_);
    {
        TJobs js;
        int t = 0;
        auto add = [&](int i, const float* in, bf16* out, int R, int C, int os) {
            js.j[i] = {in, out, R, C, os, t};
            t += (R / 32) * (C / 32);
        };
        add(0, lWq, W10, D_, HK_, D_);
        add(1, lWk, W10 + (size_t)2048 * D_, D_, HK_, D_);
        add(2, lWv, W10 + (size_t)4096 * D_, D_, HK_, D_);
        add(3, gWk, W10 + (size_t)6144 * D_, D_, HK_, D_);
        add(4, gWv, W10 + (size_t)8192 * D_, D_, HK_, D_);
        add(5, gWq, gwq_t, D_, HK_, D_);
        add(6, lWo, woL, HK_, D_, HK_);
        add(7, gWo, gwoT, HK_, D_, HK_);
        add(8, fW1, fw1_t, D_, FF_, D_);
        add(9, fW2, fw2_t, FF_, D_, FF_);
        js.total = t;
        transpose_all<<<t, dim3(32, 8), 0, stream>>>(js);
    }
    concat_bias10<<<SX_ / 256, 256, 0, stream>>>(lbq, lbk, lbv, gbk, gbv, bcat10);
    qg_kernel<<<dim3(16, 8), 256, 0, stream>>>(x, gwq_t, gbq, qg);

    // 1. single merged projection GEMM: XW = xb @ W10^T + bcat10
    gemm128<1, 128><<<dim3(SX_ / 128, BT_ / 128), 256, 0, stream>>>(xb, W10, bcat10, XW, BT_, SX_, D_);

    // 2. local path
    local_attn<<<dim3(T_ / 64, B_ * H_), 256, 0, stream>>>(XW, Ob);
    gemm128<1, 64><<<dim3(D_ / 64, BT_ / 128), 256, 0, stream>>>(Ob, woL, lbo, attnL, BT_, D_, HK_);

    // 3. global path
    g2_scores<<<dim3(B_ * H_, T_ / 256), 256, 0, stream>>>(qg, XW, sc);
    g2_softmax<<<B_ * H_, 256, 0, stream>>>(sc);
    g2_pv<<<dim3(B_ * H_, 4), 256, 0, stream>>>(sc, XW, og_part);
    g2_lin2<<<dim3(B_ * 2, 16), 256, 0, stream>>>(og_part, gwoT, gbo, g2buf);
    g2_kva2<<<dim3(16, 8), 256, 0, stream>>>(g2buf, W10 + (size_t)6144 * D_, gbk,
                                             W10 + (size_t)8192 * D_, gbv, gwq_t, gwoT, gbq, A2, W2, c2);

    // 4. LN1(+gx) + FFN + LN2
    ln1_gx<<<BT_ / 4, 256, 0, stream>>>(x, attnL, A2, W2, c2, gbo, ln1g, ln1b, out1b);
    gemm128<2, 128><<<dim3(FF_ / 128, BT_ / 128), 256, 0, stream>>>(out1b, fw1_t, fb1, hid, BT_, FF_, D_);
    gemm128<1, 64><<<dim3(D_ / 64, BT_ / 128), 256, 0, stream>>>(hid, fw2_t, fb2, ffn, BT_, D_, FF_);
    ln_kernel<bf16, false><<<BT_ / 4, 256, 0, stream>>>(out1b, ffn, nullptr, ln2g, ln2b, (float*)d_out, nullptr);
}

// Round 14
// 239.924 us; speedup vs baseline: 1.1698x; 1.0853x over previous
//
#include <hip/hip_runtime.h>
#include <hip/hip_bf16.h>

#define B_ 8
#define T_ 1024
#define D_ 256
#define H_ 8
#define KD_ 256
#define HK_ 2048
#define FF_ 1024
#define WIN_ 64
#define BT_ 8192
#define S6_ 6144   // projection row: [lQ|lK|lV]

using bf16 = __hip_bfloat16;
typedef float f32x4 __attribute__((ext_vector_type(4)));
typedef short s16x8 __attribute__((ext_vector_type(8)));

__device__ inline float b2f(bf16 h) { return __bfloat162float(h); }
__device__ inline float bs2f(short s) {
    unsigned int u = ((unsigned int)(unsigned short)s) << 16;
    return __builtin_bit_cast(float, u);
}
__device__ inline float us2f(unsigned short s) {
    unsigned int u = ((unsigned int)s) << 16;
    return __builtin_bit_cast(float, u);
}
__device__ inline unsigned short fbits(float x) { bf16 h = __float2bfloat16(x); return __builtin_bit_cast(unsigned short, h); }

// async global->LDS, 16B per lane; lds base wave-uniform, lane l lands at base + l*16
__device__ __forceinline__ void stage16(const void* g, void* l) {
    __builtin_amdgcn_global_load_lds((const __attribute__((address_space(1))) void*)g,
                                     (__attribute__((address_space(3))) void*)l, 16, 0, 0);
}

// ---------------- fused weight transposes: in f32[R][C] -> out bf16[C][R], row stride os ----------------
struct TJob { const float* in; bf16* out; int R; int C; int os; int tile_start; };
struct TJobs { TJob j[10]; int total; };

__global__ void transpose_all(TJobs js) {
    __shared__ float tile[32][33];
    int bid = blockIdx.x;
    int ji = 0;
    while (ji < 9 && bid >= js.j[ji + 1].tile_start) ji++;
    TJob jb = js.j[ji];
    int t = bid - jb.tile_start;
    int tiles_x = jb.C / 32;
    int cb = (t % tiles_x) * 32, rb = (t / tiles_x) * 32;
    for (int k = 0; k < 4; k++) {
        int r = threadIdx.y + k * 8;
        tile[r][threadIdx.x] = jb.in[(size_t)(rb + r) * jb.C + cb + threadIdx.x];
    }
    __syncthreads();
    for (int k = 0; k < 4; k++) {
        int r = threadIdx.y + k * 8;
        jb.out[(size_t)(cb + r) * jb.os + rb + threadIdx.x] = __float2bfloat16(tile[threadIdx.x][r]);
    }
}

// bias concat: bcat6[6144] = [lbq | lbk | lbv]
__global__ __launch_bounds__(256) void concat_bias6(const float* a0, const float* a1, const float* a2,
                                                    float* out) {
    int i = blockIdx.x * 256 + threadIdx.x;
    int seg = i >> 11, off = i & 2047;
    out[i] = (seg == 0 ? a0 : seg == 1 ? a1 : a2)[off];
}

// ---------------- dbuf 2-phase GEMM with T2 LDS swizzle (proven) ----------------
// C[M][N] = A[M][K] * Bt[N][K]^T + bias. 128xBN tile, BK=64, 4 waves. bf16 out.
// MODE 1: plain; MODE 2: relu.
template <int MODE, int BN>
__global__ __launch_bounds__(256) void gemm128(const bf16* __restrict__ A, const bf16* __restrict__ Bt,
                                               const float* __restrict__ bias, bf16* __restrict__ C,
                                               int M, int N, int K) {
    constexpr int NF = BN / 32;
    constexpr int ABUF = 128 * 64;
    constexpr int BBUF = BN * 64;
    constexpr int BUFE = ABUF + BBUF;
    constexpr int EC = BN + 8;
    constexpr int ARENA_E = (2 * BUFE > 128 * EC) ? 2 * BUFE : 128 * EC;
    __shared__ __align__(16) bf16 arena[ARENA_E];
    const int tid = threadIdx.x;
    const int w = tid >> 6, l = tid & 63;
    const int m0 = blockIdx.y * 128, n0 = blockIdx.x * BN;
    const int wm = (w >> 1) * 64, wn = (w & 1) * (BN / 2);
    const int srow = w * 8 + (l >> 3);
    const int scol = ((l & 7) ^ (l >> 3)) * 8;   // T2: pre-swizzled source column
    const int ldsOff = w * 512;
    const int nt = K / 64;

    auto stageT = [&](int buf, int k0) {
        bf16* Ad = arena + buf * BUFE;
        bf16* Bd = Ad + ABUF;
#pragma unroll
        for (int j = 0; j < 4; j++)
            stage16(A + (size_t)(m0 + j * 32 + srow) * K + k0 + scol, &Ad[ldsOff + j * 2048]);
#pragma unroll
        for (int j = 0; j < NF; j++)
            stage16(Bt + (size_t)(n0 + j * 32 + srow) * K + k0 + scol, &Bd[ldsOff + j * 2048]);
    };

    f32x4 acc[4][NF] = {};
    stageT(0, 0);
    __syncthreads();
    int cur = 0;
    for (int t = 0; t < nt; t++) {
        if (t + 1 < nt) stageT(cur ^ 1, (t + 1) * 64);
        const bf16* As = arena + cur * BUFE;
        const bf16* Bs = As + ABUF;
#pragma unroll
        for (int ks = 0; ks < 2; ks++) {
            s16x8 a[4], b[NF];
#pragma unroll
            for (int mf = 0; mf < 4; mf++) {
                int ar = wm + mf * 16 + (l & 15);
                int ch = (ks * 4 + (l >> 4)) ^ (ar & 7);
                a[mf] = *(const s16x8*)&As[ar * 64 + ch * 8];
            }
#pragma unroll
            for (int nf = 0; nf < NF; nf++) {
                int br = wn + nf * 16 + (l & 15);
                int ch = (ks * 4 + (l >> 4)) ^ (br & 7);
                b[nf] = *(const s16x8*)&Bs[br * 64 + ch * 8];
            }
            __builtin_amdgcn_s_setprio(1);
#pragma unroll
            for (int mf = 0; mf < 4; mf++)
#pragma unroll
                for (int nf = 0; nf < NF; nf++)
                    acc[mf][nf] = __builtin_amdgcn_mfma_f32_16x16x32_bf16(a[mf], b[nf], acc[mf][nf], 0, 0, 0);
            __builtin_amdgcn_s_setprio(0);
        }
        __syncthreads();
        cur ^= 1;
    }
    bf16* Es = arena;
#pragma unroll
    for (int mf = 0; mf < 4; mf++)
#pragma unroll
        for (int nf = 0; nf < NF; nf++)
#pragma unroll
            for (int r = 0; r < 4; r++) {
                int row = wm + mf * 16 + (l >> 4) * 4 + r;
                int col = wn + nf * 16 + (l & 15);
                float v = acc[mf][nf][r] + bias[n0 + col];
                if (MODE == 2) v = fmaxf(v, 0.f);
                Es[row * EC + col] = __float2bfloat16(v);
            }
    __syncthreads();
    constexpr int RPC = BN / 8;
    constexpr int CPT = (128 * BN) / (256 * 8);
#pragma unroll
    for (int c = 0; c < CPT; c++) {
        int lin = c * 256 + tid;
        int row = lin / RPC, cc = lin - row * RPC;
        s16x8 v = *(const s16x8*)&Es[row * EC + cc * 8];
        *(s16x8*)(C + (size_t)(m0 + row) * N + n0 + cc * 8) = v;
    }
}

// ---------------- local windowed attention (proven; stride S6_) ----------------
__global__ __launch_bounds__(256) void local_attn(const bf16* __restrict__ XW, bf16* __restrict__ O) {
    __shared__ bf16 U[256 * 72];
    __shared__ bf16 Ps[64][136];
    const int tid = threadIdx.x, l = tid & 63, w = tid >> 6;
    const int qt = blockIdx.x, bh = blockIdx.y;
    const int b = bh >> 3, h = bh & 7;
    const int qs = qt * 64;
    const int r0 = w * 16;
    const int lrow = tid >> 2, lc4 = (tid & 3) * 8;
    const size_t obase = (size_t)b * T_ * HK_ + h * KD_;

    s16x8 qa[8];
    {
        const bf16* qbase = XW + (size_t)(b * T_ + qs + r0 + (l & 15)) * S6_ + h * KD_ + (l >> 4) * 8;
#pragma unroll
        for (int ks = 0; ks < 8; ks++) qa[ks] = *(const s16x8*)(qbase + ks * 32);
    }

    bf16(*Ks)[264] = (bf16(*)[264])U;
    {
        int tk = qs - 64 + lrow;
        const bf16* krow = XW + (size_t)(b * T_ + tk) * S6_ + 2048 + h * KD_;
#pragma unroll
        for (int c = 0; c < 8; c++) {
            int col = lc4 + c * 32;
            uint4 val = {0, 0, 0, 0};
            if (tk >= 0) val = *(const uint4*)(krow + col);
            *(uint4*)&Ks[lrow][col] = val;
        }
    }
    __syncthreads();
    f32x4 sacc[8];
#pragma unroll
    for (int f = 0; f < 8; f++) sacc[f] = (f32x4){0.f, 0.f, 0.f, 0.f};
    __builtin_amdgcn_s_setprio(1);
#pragma unroll
    for (int nf = 0; nf < 4; nf++)
#pragma unroll
        for (int ks = 0; ks < 8; ks++) {
            s16x8 bb = *(const s16x8*)&Ks[nf * 16 + (l & 15)][ks * 32 + (l >> 4) * 8];
            sacc[nf] = __builtin_amdgcn_mfma_f32_16x16x32_bf16(qa[ks], bb, sacc[nf], 0, 0, 0);
        }
    __builtin_amdgcn_s_setprio(0);
    __syncthreads();
    {
        const bf16* krow = XW + (size_t)(b * T_ + qs + lrow) * S6_ + 2048 + h * KD_;
#pragma unroll
        for (int c = 0; c < 8; c++) {
            int col = lc4 + c * 32;
            *(uint4*)&Ks[lrow][col] = *(const uint4*)(krow + col);
        }
    }
    __syncthreads();
    __builtin_amdgcn_s_setprio(1);
#pragma unroll
    for (int nf = 0; nf < 4; nf++)
#pragma unroll
        for (int ks = 0; ks < 8; ks++) {
            s16x8 bb = *(const s16x8*)&Ks[nf * 16 + (l & 15)][ks * 32 + (l >> 4) * 8];
            sacc[4 + nf] = __builtin_amdgcn_mfma_f32_16x16x32_bf16(qa[ks], bb, sacc[4 + nf], 0, 0, 0);
        }
    __builtin_amdgcn_s_setprio(0);

    uint4 vreg[8];
    {
        int tk = qs - 64 + lrow;
        const bf16* vrow = XW + (size_t)(b * T_ + tk) * S6_ + 4096 + h * KD_;
#pragma unroll
        for (int c = 0; c < 8; c++) {
            uint4 v = {0, 0, 0, 0};
            if (tk >= 0) v = *(const uint4*)(vrow + lc4 + c * 32);
            vreg[c] = v;
        }
    }

#pragma unroll
    for (int r = 0; r < 4; r++) {
        int i = qs + r0 + (l >> 4) * 4 + r;
#pragma unroll
        for (int f = 0; f < 8; f++) {
            int j = qs - 64 + f * 16 + (l & 15);
            bool valid = (j >= 0) && (j <= i) && (j > i - WIN_);
            sacc[f][r] = valid ? sacc[f][r] * (1.f / 16.f) : -1e9f;
        }
        float mm = -1e30f;
#pragma unroll
        for (int f = 0; f < 8; f++) mm = fmaxf(mm, sacc[f][r]);
        mm = fmaxf(mm, __shfl_xor(mm, 1, 64));
        mm = fmaxf(mm, __shfl_xor(mm, 2, 64));
        mm = fmaxf(mm, __shfl_xor(mm, 4, 64));
        mm = fmaxf(mm, __shfl_xor(mm, 8, 64));
        float ss = 0.f;
#pragma unroll
        for (int f = 0; f < 8; f++) {
            float e = __expf(sacc[f][r] - mm);
            sacc[f][r] = e;
            ss += e;
        }
        ss += __shfl_xor(ss, 1, 64);
        ss += __shfl_xor(ss, 2, 64);
        ss += __shfl_xor(ss, 4, 64);
        ss += __shfl_xor(ss, 8, 64);
        float inv = 1.f / ss;
#pragma unroll
        for (int f = 0; f < 8; f++) sacc[f][r] *= inv;
    }
    __syncthreads();

    bf16(*VT)[72] = (bf16(*)[72])U;
#pragma unroll
    for (int f = 0; f < 8; f++)
#pragma unroll
        for (int r = 0; r < 4; r++)
            Ps[r0 + (l >> 4) * 4 + r][f * 16 + (l & 15)] = __float2bfloat16(sacc[f][r]);
#pragma unroll
    for (int c = 0; c < 8; c++) {
        int col = lc4 + c * 32;
        bf16 tmp[8];
        *(uint4*)tmp = vreg[c];
        for (int e = 0; e < 8; e++) VT[col + e][lrow] = tmp[e];
    }
    __syncthreads();
    {
        const bf16* vrow = XW + (size_t)(b * T_ + qs + lrow) * S6_ + 4096 + h * KD_;
#pragma unroll
        for (int c = 0; c < 8; c++) vreg[c] = *(const uint4*)(vrow + lc4 + c * 32);
    }

    f32x4 oacc[16];
#pragma unroll
    for (int nf = 0; nf < 16; nf++) oacc[nf] = (f32x4){0.f, 0.f, 0.f, 0.f};
    for (int kb = 0; kb < 2; kb++) {
#pragma unroll
        for (int ks = 0; ks < 2; ks++) {
            s16x8 a = *(const s16x8*)&Ps[r0 + (l & 15)][kb * 64 + ks * 32 + (l >> 4) * 8];
            __builtin_amdgcn_s_setprio(1);
#pragma unroll
            for (int nf = 0; nf < 16; nf++) {
                s16x8 bb = *(const s16x8*)&VT[nf * 16 + (l & 15)][ks * 32 + (l >> 4) * 8];
                oacc[nf] = __builtin_amdgcn_mfma_f32_16x16x32_bf16(a, bb, oacc[nf], 0, 0, 0);
            }
            __builtin_amdgcn_s_setprio(0);
        }
        if (kb == 0) {
            __syncthreads();
#pragma unroll
            for (int c = 0; c < 8; c++) {
                int col = lc4 + c * 32;
                bf16 tmp[8];
                *(uint4*)tmp = vreg[c];
                for (int e = 0; e < 8; e++) VT[col + e][lrow] = tmp[e];
            }
            __syncthreads();
        }
    }
#pragma unroll
    for (int nf = 0; nf < 16; nf++)
#pragma unroll
        for (int r = 0; r < 4; r++) {
            int row = r0 + (l >> 4) * 4 + r;
            int col = nf * 16 + (l & 15);
            O[obase + (size_t)(qs + row) * HK_ + col] = __float2bfloat16(oacc[nf][r]);
        }
}

// ---------------- global path ----------------
// qg[bi][hk] = x[b, T-2+i] . gWq[:,hk] + gbq[hk]. grid (16, 8).
__global__ __launch_bounds__(256) void qg_kernel(const float* __restrict__ x, const bf16* __restrict__ gwq_t,
                                                 const float* __restrict__ gbq, float* __restrict__ qg) {
    __shared__ float xs[256];
    int bi = blockIdx.x, ch = blockIdx.y, tid = threadIdx.x;
    int b = bi >> 1, i = bi & 1;
    xs[tid] = x[((size_t)b * T_ + (T_ - 2 + i)) * D_ + tid];
    __syncthreads();
    int hk = ch * 256 + tid;
    const bf16* wr = gwq_t + (size_t)hk * D_;
    float acc = gbq[hk];
    for (int c = 0; c < 32; c++) {
        s16x8 wv = *(const s16x8*)&wr[c * 8];
#pragma unroll
        for (int e = 0; e < 8; e++) acc += xs[c * 8 + e] * bs2f(wv[e]);
    }
    qg[(size_t)bi * HK_ + hk] = acc;
}

// qk[bi,h,d] = sum_kd qg[bi,h*256+kd] * gWk[d, h*256+kd]; cb[bi,h] = qg_h . gbk_h. grid (16,8).
__global__ __launch_bounds__(256) void qk_kernel(const float* __restrict__ qg, const bf16* __restrict__ gwk_t,
                                                 const float* __restrict__ gbk, float* __restrict__ qk,
                                                 float* __restrict__ cb) {
    __shared__ float qgs[256];
    __shared__ float red[4];
    int bi = blockIdx.x, h = blockIdx.y, tid = threadIdx.x;
    qgs[tid] = qg[(size_t)bi * HK_ + h * 256 + tid];
    __syncthreads();
    float acc = 0.f;
    const bf16* wcol = gwk_t + (size_t)(h * 256) * D_ + tid;
    for (int kd = 0; kd < 256; kd++) acc += qgs[kd] * b2f(wcol[(size_t)kd * D_]);
    qk[(size_t)(bi * 8 + h) * 256 + tid] = acc;
    float pc = qgs[tid] * gbk[h * 256 + tid];
#pragma unroll
    for (int m = 32; m >= 1; m >>= 1) pc += __shfl_xor(pc, m, 64);
    if ((tid & 63) == 0) red[tid >> 6] = pc;
    __syncthreads();
    if (tid == 0) cb[bi * 8 + h] = red[0] + red[1] + red[2] + red[3];
}

// fused x->bf16 convert + global scores: sc[(bh*2+i)*T + t] = (qk[bi,h].x_t + cb)/16.
// grid BT/4, wave per row.
__global__ __launch_bounds__(256) void conv_scores(const float* __restrict__ x, bf16* __restrict__ xb,
                                                   const float* __restrict__ qk, const float* __restrict__ cb,
                                                   float* __restrict__ sc) {
    int w = threadIdx.x >> 6, l = threadIdx.x & 63;
    int t = blockIdx.x * 4 + w;
    int b = t >> 10, tl = t & 1023;
    size_t base = (size_t)t * D_ + l * 4;
    float4 x4 = *(const float4*)(x + base);
    ushort4 o;
    o.x = fbits(x4.x); o.y = fbits(x4.y); o.z = fbits(x4.z); o.w = fbits(x4.w);
    *(ushort4*)((unsigned short*)xb + base) = o;
#pragma unroll
    for (int h = 0; h < 8; h++)
#pragma unroll
        for (int i = 0; i < 2; i++) {
            int bi = b * 2 + i;
            float4 a4 = *(const float4*)(qk + (size_t)(bi * 8 + h) * 256 + l * 4);
            float dt = x4.x * a4.x + x4.y * a4.y + x4.z * a4.z + x4.w * a4.w;
#pragma unroll
            for (int m = 32; m >= 1; m >>= 1) dt += __shfl_xor(dt, m, 64);
            if (l == 0) sc[((size_t)((b * 8 + h) * 2 + i)) * T_ + tl] = (dt + cb[bi * 8 + h]) * (1.f / 16.f);
        }
}

__global__ __launch_bounds__(256) void g2_softmax(float* __restrict__ sc) {
    __shared__ float red[4];
    int bh = blockIdx.x, tid = threadIdx.x;
    int w = tid >> 6;
    for (int i = 0; i < 2; i++) {
        float* row = &sc[((size_t)bh * 2 + i) * T_];
        float vals[4];
        float m = -1e30f;
        for (int c = 0; c < 4; c++) {
            vals[c] = row[tid + 256 * c];
            m = fmaxf(m, vals[c]);
        }
        for (int s = 32; s >= 1; s >>= 1) m = fmaxf(m, __shfl_xor(m, s, 64));
        if ((tid & 63) == 0) red[w] = m;
        __syncthreads();
        m = fmaxf(fmaxf(red[0], red[1]), fmaxf(red[2], red[3]));
        __syncthreads();
        float s = 0.f;
        for (int c = 0; c < 4; c++) {
            vals[c] = __expf(vals[c] - m);
            s += vals[c];
        }
        for (int d = 32; d >= 1; d >>= 1) s += __shfl_xor(s, d, 64);
        if ((tid & 63) == 0) red[w] = s;
        __syncthreads();
        s = red[0] + red[1] + red[2] + red[3];
        float inv = 1.f / s;
        for (int c = 0; c < 4; c++) row[tid + 256 * c] = vals[c] * inv;
        __syncthreads();
    }
}

// xbar partials: xbar_part[(bh*4+ch)*2+i][d] = sum_{t in chunk} p[bh,i,t] * x[b,t,d]. grid (64,4).
__global__ __launch_bounds__(256) void xbar_kernel(const float* __restrict__ sc, const float* __restrict__ x,
                                                   float* __restrict__ xbar_part) {
    __shared__ float p2[2][256];
    int bh = blockIdx.x, ch = blockIdx.y;
    int b = bh >> 3;
    int tid = threadIdx.x;
    for (int i = 0; i < 2; i++) p2[i][tid] = sc[((size_t)bh * 2 + i) * T_ + ch * 256 + tid];
    __syncthreads();
    const float* xp = x + ((size_t)(b * T_ + ch * 256)) * D_ + tid;
    float a0 = 0.f, a1 = 0.f;
    for (int t = 0; t < 256; t++) {
        float xv = xp[(size_t)t * D_];
        a0 += p2[0][t] * xv;
        a1 += p2[1][t] * xv;
    }
    xbar_part[((size_t)(bh * 4 + ch) * 2 + 0) * KD_ + tid] = a0;
    xbar_part[((size_t)(bh * 4 + ch) * 2 + 1) * KD_ + tid] = a1;
}

// og2[bi][h*256+kd] = xbar[b,h,i] . gWv[:, h*256+kd] + gbv. grid (16, 8).
__global__ __launch_bounds__(256) void g2_vo(const float* __restrict__ xbar_part, const bf16* __restrict__ gwv_t,
                                             const float* __restrict__ gbv, float* __restrict__ og2) {
    __shared__ float xbs[256];
    int bi = blockIdx.x, h = blockIdx.y, tid = threadIdx.x;
    int b = bi >> 1, i = bi & 1;
    int bh = b * 8 + h;
    float s = 0.f;
#pragma unroll
    for (int ch = 0; ch < 4; ch++) s += xbar_part[((size_t)(bh * 4 + ch) * 2 + i) * KD_ + tid];
    xbs[tid] = s;
    __syncthreads();
    int hk = h * 256 + tid;
    const bf16* wr = gwv_t + (size_t)hk * D_;
    float acc = gbv[hk];
    for (int c = 0; c < 32; c++) {
        s16x8 wv = *(const s16x8*)&wr[c * 8];
#pragma unroll
        for (int e = 0; e < 8; e++) acc += xbs[c * 8 + e] * bs2f(wv[e]);
    }
    og2[(size_t)bi * HK_ + hk] = acc;
}

// g2buf[bi][d] = og2[bi][:] . gwoT[d][:] + gbo[d]. grid (16,16).
__global__ __launch_bounds__(256) void g2_lin2(const float* __restrict__ og2, const bf16* __restrict__ gwoT,
                                               const float* __restrict__ gbo, float* __restrict__ g2buf) {
    int bi = blockIdx.x, tid = threadIdx.x;
    int d = blockIdx.y * 16 + (tid >> 4);
    int s16i = tid & 15;
    const float* ogr = og2 + (size_t)bi * 2048 + s16i * 128;
    const bf16* wr = gwoT + (size_t)d * HK_ + s16i * 128;
    float acc = 0.f;
    for (int c = 0; c < 16; c++) {
        s16x8 wv = *(const s16x8*)&wr[c * 8];
#pragma unroll
        for (int e = 0; e < 8; e++) acc += ogr[c * 8 + e] * bs2f(wv[e]);
    }
    acc += __shfl_xor(acc, 1, 64);
    acc += __shfl_xor(acc, 2, 64);
    acc += __shfl_xor(acc, 4, 64);
    acc += __shfl_xor(acc, 8, 64);
    if (s16i == 0) g2buf[(size_t)bi * 256 + d] = acc + gbo[d];
}

// merged g2_kv + a2w2: grid (16, 8). K2/V2 head-slice in LDS, then A2/W2/c2.
__global__ __launch_bounds__(256) void g2_kva2(const float* __restrict__ g2buf, const bf16* __restrict__ gwk_t,
                                               const float* __restrict__ gbk, const bf16* __restrict__ gwv_t,
                                               const float* __restrict__ gbv, const bf16* __restrict__ gwq_t,
                                               const bf16* __restrict__ gwoT, const float* __restrict__ gbq,
                                               float* __restrict__ A2, float* __restrict__ W2,
                                               float* __restrict__ c2) {
    __shared__ float g2s[256], k2s[256], v2s[256];
    __shared__ float red[4];
    int bi = blockIdx.x, h = blockIdx.y, tid = threadIdx.x;
    g2s[tid] = g2buf[(size_t)bi * 256 + tid];
    __syncthreads();
    int hk = h * 256 + tid;
    {
        const bf16* rk = &gwk_t[(size_t)hk * D_];
        const bf16* rv = &gwv_t[(size_t)hk * D_];
        float ak = gbk[hk], av = gbv[hk];
        for (int c = 0; c < 32; c++) {
            s16x8 kw = *(const s16x8*)&rk[c * 8];
            s16x8 vw = *(const s16x8*)&rv[c * 8];
#pragma unroll
            for (int e = 0; e < 8; e++) {
                float g = g2s[c * 8 + e];
                ak += g * bs2f(kw[e]);
                av += g * bs2f(vw[e]);
            }
        }
        k2s[tid] = ak;
        v2s[tid] = av;
    }
    __syncthreads();
    float accA = 0.f;
    const bf16* wq = gwq_t + (size_t)(h * 256) * D_ + tid;
    for (int kd = 0; kd < 256; kd++)
        accA += k2s[kd] * b2f(wq[(size_t)kd * D_]);
    float accW = 0.f;
    const bf16* wo = gwoT + (size_t)tid * HK_ + h * 256;
    for (int c = 0; c < 32; c++) {
        s16x8 wv = *(const s16x8*)&wo[c * 8];
#pragma unroll
        for (int e = 0; e < 8; e++) accW += v2s[c * 8 + e] * bs2f(wv[e]);
    }
    int o = (bi * 8 + h) * 256 + tid;
    A2[o] = accA;
    W2[o] = accW;
    float pc = gbq[h * 256 + tid] * k2s[tid];
#pragma unroll
    for (int m = 32; m >= 1; m >>= 1) pc += __shfl_xor(pc, m, 64);
    if ((tid & 63) == 0) red[tid >> 6] = pc;
    __syncthreads();
    if (tid == 0) c2[bi * 8 + h] = red[0] + red[1] + red[2] + red[3];
}

// ---------------- LN1 with inline gx: out1b = LN(x + attnL + gx(x)). grid BT/4, wave/row ----------------
__global__ __launch_bounds__(256) void ln1_gx(const float* __restrict__ x, const bf16* __restrict__ attnL,
                                              const float* __restrict__ A2, const float* __restrict__ W2,
                                              const float* __restrict__ c2, const float* __restrict__ gbo,
                                              const float* __restrict__ g, const float* __restrict__ bia,
                                              bf16* __restrict__ outb) {
    int w = threadIdx.x >> 6, l = threadIdx.x & 63;
    int t = blockIdx.x * 4 + w;
    int b = t >> 10;
    size_t base = (size_t)t * D_ + l * 4;
    float4 x4 = *(const float4*)(x + base);
    float p[8][2];
#pragma unroll
    for (int h = 0; h < 8; h++)
#pragma unroll
        for (int i = 0; i < 2; i++) {
            float4 a4 = *(const float4*)(A2 + ((size_t)((b * 2 + i) * 8 + h)) * 256 + l * 4);
            float dt = x4.x * a4.x + x4.y * a4.y + x4.z * a4.z + x4.w * a4.w;
#pragma unroll
            for (int m = 32; m >= 1; m >>= 1) dt += __shfl_xor(dt, m, 64);
            p[h][i] = dt;
        }
    float4 gb = *(const float4*)(gbo + l * 4);
    float o0 = gb.x, o1 = gb.y, o2 = gb.z, o3 = gb.w;
#pragma unroll
    for (int h = 0; h < 8; h++) {
        float s0 = (p[h][0] + c2[(b * 2 + 0) * 8 + h]) * (1.f / 16.f);
        float s1 = (p[h][1] + c2[(b * 2 + 1) * 8 + h]) * (1.f / 16.f);
        float mx = fmaxf(s0, s1);
        float e0 = __expf(s0 - mx), e1 = __expf(s1 - mx);
        float inv = 1.f / (e0 + e1);
        float p0 = e0 * inv, p1 = e1 * inv;
        float4 w0 = *(const float4*)(W2 + ((size_t)((b * 2 + 0) * 8 + h)) * 256 + l * 4);
        float4 w1 = *(const float4*)(W2 + ((size_t)((b * 2 + 1) * 8 + h)) * 256 + l * 4);
        o0 += p0 * w0.x + p1 * w1.x;
        o1 += p0 * w0.y + p1 * w1.y;
        o2 += p0 * w0.z + p1 * w1.z;
        o3 += p0 * w0.w + p1 * w1.w;
    }
    ushort4 av = *(const ushort4*)((const unsigned short*)attnL + base);
    float vv[4];
    vv[0] = x4.x + us2f(av.x) + o0;
    vv[1] = x4.y + us2f(av.y) + o1;
    vv[2] = x4.z + us2f(av.z) + o2;
    vv[3] = x4.w + us2f(av.w) + o3;
    float s = vv[0] + vv[1] + vv[2] + vv[3];
#pragma unroll
    for (int m = 32; m >= 1; m >>= 1) s += __shfl_xor(s, m, 64);
    float mean = s * (1.f / 256.f);
    float q = 0.f;
#pragma unroll
    for (int e = 0; e < 4; e++) {
        float d = vv[e] - mean;
        q += d * d;
    }
#pragma unroll
    for (int m = 32; m >= 1; m >>= 1) q += __shfl_xor(q, m, 64);
    float rs = rsqrtf(q * (1.f / 256.f) + 1e-6f);
    float4 gv = *(const float4*)(g + l * 4);
    float4 biv = *(const float4*)(bia + l * 4);
    ushort4 ou;
    ou.x = fbits((vv[0] - mean) * rs * gv.x + biv.x);
    ou.y = fbits((vv[1] - mean) * rs * gv.y + biv.y);
    ou.z = fbits((vv[2] - mean) * rs * gv.z + biv.z);
    ou.w = fbits((vv[3] - mean) * rs * gv.w + biv.w);
    *(ushort4*)((unsigned short*)outb + base) = ou;
}

// ---------------- LayerNorm over D=256: wave per row (LN2) ----------------
template <typename TA, bool HASC>
__global__ __launch_bounds__(256) void ln_kernel(const TA* __restrict__ a, const bf16* __restrict__ b2,
                                                 const bf16* __restrict__ c, const float* __restrict__ g,
                                                 const float* __restrict__ bia, float* __restrict__ outf,
                                                 bf16* __restrict__ outb) {
    int w = threadIdx.x >> 6, l = threadIdx.x & 63;
    int row = blockIdx.x * 4 + w;
    size_t base = (size_t)row * D_ + l * 4;
    float vv[4];
    if constexpr (sizeof(TA) == 4) {
        float4 av = *(const float4*)((const float*)a + base);
        vv[0] = av.x; vv[1] = av.y; vv[2] = av.z; vv[3] = av.w;
    } else {
        ushort4 av = *(const ushort4*)((const unsigned short*)a + base);
        vv[0] = us2f(av.x); vv[1] = us2f(av.y); vv[2] = us2f(av.z); vv[3] = us2f(av.w);
    }
    ushort4 bv = *(const ushort4*)((const unsigned short*)b2 + base);
    vv[0] += us2f(bv.x); vv[1] += us2f(bv.y); vv[2] += us2f(bv.z); vv[3] += us2f(bv.w);
    if constexpr (HASC) {
        ushort4 cv = *(const ushort4*)((const unsigned short*)c + base);
        vv[0] += us2f(cv.x); vv[1] += us2f(cv.y); vv[2] += us2f(cv.z); vv[3] += us2f(cv.w);
    }
    float s = vv[0] + vv[1] + vv[2] + vv[3];
#pragma unroll
    for (int m = 32; m >= 1; m >>= 1) s += __shfl_xor(s, m, 64);
    float mean = s * (1.f / 256.f);
    float q = 0.f;
#pragma unroll
    for (int e = 0; e < 4; e++) {
        float d = vv[e] - mean;
        q += d * d;
    }
#pragma unroll
    for (int m = 32; m >= 1; m >>= 1) q += __shfl_xor(q, m, 64);
    float rs = rsqrtf(q * (1.f / 256.f) + 1e-6f);
    float4 gv = *(const float4*)(g + l * 4);
    float4 biv = *(const float4*)(bia + l * 4);
    float o0 = (vv[0] - mean) * rs * gv.x + biv.x;
    float o1 = (vv[1] - mean) * rs * gv.y + biv.y;
    float o2 = (vv[2] - mean) * rs * gv.z + biv.z;
    float o3 = (vv[3] - mean) * rs * gv.w + biv.w;
    if (outf) *(float4*)(outf + base) = (float4){o0, o1, o2, o3};
    if (outb) {
        ushort4 ou;
        ou.x = fbits(o0); ou.y = fbits(o1); ou.z = fbits(o2); ou.w = fbits(o3);
        *(ushort4*)(outb + base) = ou;
    }
}

extern "C" void kernel_launch(void* const* d_in, const int* in_sizes, int n_in, void* d_out, int out_size,
                              void* d_ws, size_t ws_size, hipStream_t stream) {
    const float* x = (const float*)d_in[0];
    const float* lWq = (const float*)d_in[1];  const float* lbq = (const float*)d_in[2];
    const float* lWk = (const float*)d_in[3];  const float* lbk = (const float*)d_in[4];
    const float* lWv = (const float*)d_in[5];  const float* lbv = (const float*)d_in[6];
    const float* lWo = (const float*)d_in[7];  const float* lbo = (const float*)d_in[8];
    const float* gWq = (const float*)d_in[9];  const float* gbq = (const float*)d_in[10];
    const float* gWk = (const float*)d_in[11]; const float* gbk = (const float*)d_in[12];
    const float* gWv = (const float*)d_in[13]; const float* gbv = (const float*)d_in[14];
    const float* gWo = (const float*)d_in[15]; const float* gbo = (const float*)d_in[16];
    const float* fW1 = (const float*)d_in[17]; const float* fb1 = (const float*)d_in[18];
    const float* fW2 = (const float*)d_in[19]; const float* fb2 = (const float*)d_in[20];
    const float* ln1g = (const float*)d_in[21]; const float* ln1b = (const float*)d_in[22];
    const float* ln2g = (const float*)d_in[23]; const float* ln2b = (const float*)d_in[24];

    char* ws = (char*)d_ws;
    size_t off = 0;
    auto alloc = [&](size_t bytes) -> char* {
        char* p = ws + off;
        off = (off + bytes + 255) & ~(size_t)255;
        return p;
    };
    bf16* xb = (bf16*)alloc((size_t)BT_ * D_ * 2);
    bf16* W6 = (bf16*)alloc((size_t)S6_ * D_ * 2);      // [lWq|lWk|lWv]^T
    bf16* gwq_t = (bf16*)alloc((size_t)HK_ * D_ * 2);   // gWq^T
    bf16* gwk_t = (bf16*)alloc((size_t)HK_ * D_ * 2);   // gWk^T
    bf16* gwv_t = (bf16*)alloc((size_t)HK_ * D_ * 2);   // gWv^T
    bf16* woL = (bf16*)alloc((size_t)D_ * HK_ * 2);     // lWo^T
    bf16* gwoT = (bf16*)alloc((size_t)D_ * HK_ * 2);    // gWo^T
    bf16* fw1_t = (bf16*)alloc((size_t)FF_ * D_ * 2);
    bf16* fw2_t = (bf16*)alloc((size_t)D_ * FF_ * 2);
    float* bcat6 = (float*)alloc((size_t)S6_ * 4);
    bf16* XW = (bf16*)alloc((size_t)BT_ * S6_ * 2);     // 96 MB projection output [lQ|lK|lV]
    bf16* Ob = (bf16*)alloc((size_t)BT_ * HK_ * 2);     // 32 MB local attn out
    bf16* attnL = (bf16*)alloc((size_t)BT_ * D_ * 2);
    float* sc = (float*)alloc((size_t)B_ * H_ * 2 * T_ * 4);
    float* xbar_part = (float*)alloc((size_t)B_ * H_ * 4 * 2 * KD_ * 4);
    float* og2 = (float*)alloc((size_t)16 * HK_ * 4);
    float* g2buf = (float*)alloc((size_t)B_ * 2 * D_ * 4);
    float* qg = (float*)alloc((size_t)B_ * 2 * HK_ * 4);
    float* qk = (float*)alloc((size_t)16 * 8 * 256 * 4);
    float* cb = (float*)alloc((size_t)16 * 8 * 4);
    float* A2 = (float*)alloc((size_t)16 * 8 * 256 * 4);
    float* W2 = (float*)alloc((size_t)16 * 8 * 256 * 4);
    float* c2 = (float*)alloc((size_t)16 * 8 * 4);
    // aliases into XW (XW dead after local_attn):
    bf16* hid = XW;                                     // [8192][1024] bf16, 16 MB @ 0
    bf16* ffn = (bf16*)((char*)XW + (32u << 20));       // 4 MB @ 32M
    bf16* out1b = (bf16*)((char*)XW + (48u << 20));     // 4 MB @ 48M

    // 0. transposes + biases + tiny global-path precomputes
    {
        TJobs js;
        int t = 0;
        auto add = [&](int i, const float* in, bf16* out, int R, int C, int os) {
            js.j[i] = {in, out, R, C, os, t};
            t += (R / 32) * (C / 32);
        };
        add(0, lWq, W6, D_, HK_, D_);
        add(1, lWk, W6 + (size_t)2048 * D_, D_, HK_, D_);
        add(2, lWv, W6 + (size_t)4096 * D_, D_, HK_, D_);
        add(3, gWq, gwq_t, D_, HK_, D_);
        add(4, gWk, gwk_t, D_, HK_, D_);
        add(5, gWv, gwv_t, D_, HK_, D_);
        add(6, lWo, woL, HK_, D_, HK_);
        add(7, gWo, gwoT, HK_, D_, HK_);
        add(8, fW1, fw1_t, D_, FF_, D_);
        add(9, fW2, fw2_t, FF_, D_, FF_);
        js.total = t;
        transpose_all<<<t, dim3(32, 8), 0, stream>>>(js);
    }
    concat_bias6<<<S6_ / 256, 256, 0, stream>>>(lbq, lbk, lbv, bcat6);
    qg_kernel<<<dim3(16, 8), 256, 0, stream>>>(x, gwq_t, gbq, qg);
    qk_kernel<<<dim3(16, 8), 256, 0, stream>>>(qg, gwk_t, gbk, qk, cb);

    // 1. fused convert + global scores (streams x once)
    conv_scores<<<BT_ / 4, 256, 0, stream>>>(x, xb, qk, cb, sc);

    // 2. local projection GEMM: XW = xb @ W6^T + bcat6
    gemm128<1, 128><<<dim3(S6_ / 128, BT_ / 128), 256, 0, stream>>>(xb, W6, bcat6, XW, BT_, S6_, D_);

    // 3. local path
    local_attn<<<dim3(T_ / 64, B_ * H_), 256, 0, stream>>>(XW, Ob);
    gemm128<1, 64><<<dim3(D_ / 64, BT_ / 128), 256, 0, stream>>>(Ob, woL, lbo, attnL, BT_, D_, HK_);

    // 4. global path (tiny)
    g2_softmax<<<B_ * H_, 256, 0, stream>>>(sc);
    xbar_kernel<<<dim3(B_ * H_, 4), 256, 0, stream>>>(sc, x, xbar_part);
    g2_vo<<<dim3(16, 8), 256, 0, stream>>>(xbar_part, gwv_t, gbv, og2);
    g2_lin2<<<dim3(16, 16), 256, 0, stream>>>(og2, gwoT, gbo, g2buf);
    g2_kva2<<<dim3(16, 8), 256, 0, stream>>>(g2buf, gwk_t, gbk, gwv_t, gbv, gwq_t, gwoT, gbq, A2, W2, c2);

    // 5. LN1(+gx) + FFN + LN2
    ln1_gx<<<BT_ / 4, 256, 0, stream>>>(x, attnL, A2, W2, c2, gbo, ln1g, ln1b, out1b);
    gemm128<2, 128><<<dim3(FF_ / 128, BT_ / 128), 256, 0, stream>>>(out1b, fw1_t, fb1, hid, BT_, FF_, D_);
    gemm128<1, 64><<<dim3(D_ / 64, BT_ / 128), 256, 0, stream>>>(hid, fw2_t, fb2, ffn, BT_, D_, FF_);
    ln_kernel<bf16, false><<<BT_ / 4, 256, 0, stream>>>(out1b, ffn, nullptr, ln2g, ln2b, (float*)d_out, nullptr);
}